// Round 2
// baseline (4156.284 us; speedup 1.0000x reference)
//
#include <hip/hip_runtime.h>
#include <hip/hip_bf16.h>
#include <stdint.h>
#include <stddef.h>

static constexpr int BB = 16, NN = 256, TT = 4, HH = 128;
static constexpr int MM = BB * NN;     // 4096 rows
static constexpr int CC = 512;         // 4*H gate width
static constexpr int OUTV = 1000;
static constexpr int MAXS = 15;

__device__ __forceinline__ float sigmoidf(float x) { return 1.0f / (1.0f + __expf(-x)); }

// ---------------- setup kernels ----------------

// zero the 4 contiguous state buffers (Sc0,Sh0,Sc1,Sh1), init ip, zero CSR counts
__global__ void init_kernel(float* __restrict__ S, float* __restrict__ ip, int* __restrict__ count) {
  int tid = blockIdx.x * blockDim.x + threadIdx.x;
  int stride = gridDim.x * blockDim.x;
  int total = 4 * MM * HH;
  for (int i = tid; i < total; i += stride) S[i] = 0.0f;
  for (int i = tid; i < MM; i += stride) {
    ip[i] = ((i & (NN - 1)) == 0) ? 1.0f : 0.0f;
    count[i] = 0;
  }
}

// embT[t][m][j] = embed[data[m][t]][j]  (token-gathered embeddings, step-invariant)
__global__ void gather_emb(const int* __restrict__ data, const float* __restrict__ embed,
                           float* __restrict__ embT) {
  int tid = blockIdx.x * blockDim.x + threadIdx.x;
  int stride = gridDim.x * blockDim.x;
  const int total = TT * MM * HH;  // all pow2
  for (int i = tid; i < total; i += stride) {
    int j = i & (HH - 1);
    int m = (i >> 7) & (MM - 1);
    int t = i >> 19;  // i / (MM*HH)
    int tok = data[m * TT + t];
    embT[i] = embed[(size_t)tok * HH + j];
  }
}

// CSR build over the fixed branch graph: 2 edges per (b,n)
__global__ void edge_count(const int* __restrict__ tb, const int* __restrict__ fb,
                           int* __restrict__ count) {
  int e = blockIdx.x * blockDim.x + threadIdx.x;
  if (e >= 2 * MM) return;
  int b = e >> 9, r = e & 511, n = r >> 1, bit = r & 1;
  int tgt = bit ? fb[b * NN + n] : tb[b * NN + n];
  atomicAdd(&count[b * NN + tgt], 1);
}

__global__ void edge_scan(int* __restrict__ count, int* __restrict__ offs) {
  int b = blockIdx.x, tid = threadIdx.x;
  __shared__ int s[256];
  int v = count[b * NN + tid];
  s[tid] = v;
  __syncthreads();
  for (int off = 1; off < 256; off <<= 1) {
    int t = (tid >= off) ? s[tid - off] : 0;
    __syncthreads();
    s[tid] += t;
    __syncthreads();
  }
  offs[b * NN + tid] = b * 2 * NN + s[tid] - v;  // exclusive scan + per-batch base
  count[b * NN + tid] = 0;                        // reuse as fill cursor
  if (b == 0 && tid == 0) offs[MM] = 2 * MM;
}

__global__ void edge_fill(const int* __restrict__ tb, const int* __restrict__ fb,
                          const int* __restrict__ offs, int* __restrict__ cursor,
                          int* __restrict__ edges) {
  int e = blockIdx.x * blockDim.x + threadIdx.x;
  if (e >= 2 * MM) return;
  int b = e >> 9, r = e & 511, n = r >> 1, bit = r & 1;
  int tgt = bit ? fb[b * NN + n] : tb[b * NN + n];
  int pos = offs[b * NN + tgt] + atomicAdd(&cursor[b * NN + tgt], 1);
  edges[pos] = (n << 1) | bit;
}

// ---------------- per-step kernels ----------------

// One LSTM cell for 8 rows/block, 128 threads (thread j = gate element j).
// z = A1@W1 + A2@W2 + bias; then gate math; in-place-safe per row (each block
// reads only the rows it writes, reads complete before writes).
__global__ void lstm_kernel(const float* __restrict__ A1, const float* __restrict__ W1,
                            const float* __restrict__ A2, const float* __restrict__ W2,
                            const float* __restrict__ bias,
                            const float* __restrict__ c_in, float* __restrict__ c_out,
                            float* __restrict__ h_out,
                            const int* __restrict__ steps, int step) {
  const int row0 = blockIdx.x * 8;
  if (step >= steps[row0 >> 8]) return;  // dead batch: result would be discarded
  const int j = threadIdx.x;
  __shared__ float a1[8][128];
  __shared__ float a2s[8][128];
#pragma unroll
  for (int r = 0; r < 8; ++r) a1[r][j] = A1[(size_t)(row0 + r) * HH + j];
#pragma unroll
  for (int r = 0; r < 8; ++r) a2s[r][j] = A2[(size_t)(row0 + r) * HH + j];
  __syncthreads();

  float zi[8], zf[8], zg[8], zo[8];
  {
    float bi = bias[j], bfv = bias[128 + j], bg = bias[256 + j], bov = bias[384 + j];
#pragma unroll
    for (int r = 0; r < 8; ++r) { zi[r] = bi; zf[r] = bfv; zg[r] = bg; zo[r] = bov; }
  }

#pragma unroll 4
  for (int k = 0; k < HH; ++k) {
    float wi = W1[k * CC + j], wf = W1[k * CC + 128 + j];
    float wg = W1[k * CC + 256 + j], wo = W1[k * CC + 384 + j];
#pragma unroll
    for (int r = 0; r < 8; ++r) {
      float av = a1[r][k];
      zi[r] += av * wi; zf[r] += av * wf; zg[r] += av * wg; zo[r] += av * wo;
    }
  }
#pragma unroll 4
  for (int k = 0; k < HH; ++k) {
    float wi = W2[k * CC + j], wf = W2[k * CC + 128 + j];
    float wg = W2[k * CC + 256 + j], wo = W2[k * CC + 384 + j];
#pragma unroll
    for (int r = 0; r < 8; ++r) {
      float av = a2s[r][k];
      zi[r] += av * wi; zf[r] += av * wf; zg[r] += av * wg; zo[r] += av * wo;
    }
  }

#pragma unroll
  for (int r = 0; r < 8; ++r) {
    size_t idx = (size_t)(row0 + r) * HH + j;
    float c = c_in[idx];
    float cn = sigmoidf(zf[r]) * c + sigmoidf(zi[r]) * tanhf(zg[r]);
    float hn = sigmoidf(zo[r]) * tanhf(cn);
    c_out[idx] = cn;
    h_out[idx] = hn;
  }
}

// restore pre-execute state at each batch's exit node (working copies only)
__global__ void exit_restore(const float* __restrict__ Sc0, const float* __restrict__ Sh0,
                             const float* __restrict__ Sc1, const float* __restrict__ Sh1,
                             float* __restrict__ Wc0, float* __restrict__ Wh0,
                             float* __restrict__ Wc1, float* __restrict__ Wh1,
                             const int* __restrict__ exi, const int* __restrict__ steps, int step) {
  int b = blockIdx.x;
  if (step >= steps[b]) return;
  int j = threadIdx.x;
  size_t idx = (size_t)(b * NN + exi[b]) * HH + j;
  Wc0[idx] = Sc0[idx]; Wh0[idx] = Sh0[idx];
  Wc1[idx] = Sc1[idx]; Wh1[idx] = Sh1[idx];
}

// branch logits over feats=[c0,h0,c1,h1] (512) -> softmax -> wt,wf. One wave per row.
__global__ void branch_kernel(const float* __restrict__ Wc0, const float* __restrict__ Wh0,
                              const float* __restrict__ Wc1, const float* __restrict__ Wh1,
                              const float* __restrict__ Wb, const float* __restrict__ bb,
                              const float* __restrict__ ip, float* __restrict__ wt,
                              float* __restrict__ wf,
                              const int* __restrict__ steps, int step) {
  const int row = blockIdx.x * 4 + (threadIdx.x >> 6);
  if (step >= steps[row >> 8]) return;
  const int lane = threadIdx.x & 63;
  float z0 = 0.f, z1 = 0.f;
#pragma unroll
  for (int u = 0; u < 8; ++u) {
    int k = u * 64 + lane;
    float fk;
    if (k < 128)      fk = Wc0[(size_t)row * HH + k];
    else if (k < 256) fk = Wh0[(size_t)row * HH + k - 128];
    else if (k < 384) fk = Wc1[(size_t)row * HH + k - 256];
    else              fk = Wh1[(size_t)row * HH + k - 384];
    z0 += fk * Wb[2 * k];
    z1 += fk * Wb[2 * k + 1];
  }
#pragma unroll
  for (int off = 32; off > 0; off >>= 1) {
    z0 += __shfl_xor(z0, off, 64);
    z1 += __shfl_xor(z1, off, 64);
  }
  if (lane == 0) {
    z0 += bb[0]; z1 += bb[1];
    float m = fmaxf(z0, z1);
    float e0 = __expf(z0 - m), e1 = __expf(z1 - m);
    float inv = 1.0f / (e0 + e1);
    float ipv = ip[row];
    wt[row] = e0 * inv * ipv;
    wf[row] = e1 * inv * ipv;
  }
}

// CSR gather aggregation: S[b,v,:] = (sum_e w_e * W[b,src_e,:]) / (wsum+1e-7); ip update.
__global__ void agg_kernel(const int* __restrict__ offs, const int* __restrict__ edges,
                           const float* __restrict__ wt, const float* __restrict__ wf,
                           const float* __restrict__ Wc0, const float* __restrict__ Wh0,
                           const float* __restrict__ Wc1, const float* __restrict__ Wh1,
                           float* __restrict__ Sc0, float* __restrict__ Sh0,
                           float* __restrict__ Sc1, float* __restrict__ Sh1,
                           float* __restrict__ ip,
                           const int* __restrict__ steps, int step) {
  const int idx = blockIdx.x;  // b*256 + v
  const int b = idx >> 8;
  if (step >= steps[b]) return;
  const int j = threadIdx.x;
  const int beg = offs[idx], end = offs[idx + 1];
  float ac0 = 0.f, ah0 = 0.f, ac1 = 0.f, ah1 = 0.f, wsum = 0.f;
  for (int e = beg; e < end; ++e) {
    int rec = edges[e];
    int src = (b << 8) + (rec >> 1);
    float w = (rec & 1) ? wf[src] : wt[src];
    wsum += w;
    size_t sb = (size_t)src * HH + j;
    ac0 += w * Wc0[sb]; ah0 += w * Wh0[sb];
    ac1 += w * Wc1[sb]; ah1 += w * Wh1[sb];
  }
  float inv = 1.0f / (wsum + 1e-7f);
  size_t db = (size_t)idx * HH + j;
  Sc0[db] = ac0 * inv; Sh0[db] = ah0 * inv;
  Sc1[db] = ac1 * inv; Sh1[db] = ah1 * inv;
  if (j == 0) ip[idx] = wsum;
}

// logits[b,:] = [c0,h0,c1,h1](exit) @ Wo + bo  -> f32 out
__global__ void final_kernel(const float* __restrict__ Sc0, const float* __restrict__ Sh0,
                             const float* __restrict__ Sc1, const float* __restrict__ Sh1,
                             const int* __restrict__ exi, const float* __restrict__ Wo,
                             const float* __restrict__ bo, float* __restrict__ out) {
  const int b = blockIdx.x;
  const int tid = threadIdx.x;  // 256
  __shared__ float f[512];
  int row = b * NN + exi[b];
  for (int i = tid; i < 512; i += 256) {
    int seg = i >> 7, k = i & 127;
    const float* S = (seg == 0) ? Sc0 : (seg == 1) ? Sh0 : (seg == 2) ? Sc1 : Sh1;
    f[i] = S[(size_t)row * HH + k];
  }
  __syncthreads();
  for (int v = tid; v < OUTV; v += 256) {
    float acc = bo[v];
    for (int k = 0; k < 512; ++k) acc += f[k] * Wo[(size_t)k * OUTV + v];
    out[b * OUTV + v] = acc;
  }
}

// distinct failure signature if workspace is too small: out := 0 -> err == ref absmax
__global__ void zero_out_kernel(float* __restrict__ out, int n) {
  int i = blockIdx.x * blockDim.x + threadIdx.x;
  if (i < n) out[i] = 0.0f;
}

// ---------------- host orchestration ----------------

extern "C" void kernel_launch(void* const* d_in, const int* in_sizes, int n_in,
                              void* d_out, int out_size, void* d_ws, size_t ws_size,
                              hipStream_t stream) {
  const int* data = (const int*)d_in[0];
  const int* tb   = (const int*)d_in[1];
  const int* fb   = (const int*)d_in[2];
  const int* exi  = (const int*)d_in[3];
  const int* steps = (const int*)d_in[4];
  const float* embed = (const float*)d_in[5];
  const float* Wi = (const float*)d_in[6];   // (L,H,4H)
  const float* Wh = (const float*)d_in[7];   // (L,H,4H)
  const float* bl = (const float*)d_in[8];   // (L,4H)
  const float* Wb = (const float*)d_in[9];   // (2LH,2)
  const float* bb = (const float*)d_in[10];  // (2,)
  const float* Wo = (const float*)d_in[11];  // (2LH,OUT)
  const float* bo = (const float*)d_in[12];  // (OUT,)
  float* out = (float*)d_out;

  const float* Wi0 = Wi;              // layer 0 input weights
  const float* Wi1 = Wi + HH * CC;    // layer 1 input weights
  const float* Wh0 = Wh;
  const float* Wh1 = Wh + HH * CC;
  const float* b0 = bl;
  const float* b1 = bl + CC;

  float* ws = (float*)d_ws;
  size_t off = 0;
  float* embT = ws + off; off += (size_t)TT * MM * HH;     // 2.1M floats (8 MB)
  float* Sc0 = ws + off;  off += (size_t)MM * HH;          // 4 contiguous state bufs
  float* Sh0 = ws + off;  off += (size_t)MM * HH;
  float* Sc1 = ws + off;  off += (size_t)MM * HH;
  float* Sh1 = ws + off;  off += (size_t)MM * HH;
  float* Wc0 = ws + off;  off += (size_t)MM * HH;          // 4 working bufs
  float* Wh0w = ws + off; off += (size_t)MM * HH;
  float* Wc1 = ws + off;  off += (size_t)MM * HH;
  float* Wh1w = ws + off; off += (size_t)MM * HH;
  float* ip = ws + off;   off += MM;
  float* wt = ws + off;   off += MM;
  float* wf = ws + off;   off += MM;
  int* count = (int*)(ws + off); off += MM;
  int* offs  = (int*)(ws + off); off += MM + 4;
  int* edges = (int*)(ws + off); off += 2 * MM;
  (void)in_sizes; (void)n_in; (void)out_size;

  if (ws_size < off * sizeof(float)) {
    zero_out_kernel<<<(BB * OUTV + 255) / 256, 256, 0, stream>>>(out, BB * OUTV);
    return;
  }

  init_kernel<<<256, 256, 0, stream>>>(Sc0, ip, count);
  gather_emb<<<512, 256, 0, stream>>>(data, embed, embT);
  edge_count<<<(2 * MM + 255) / 256, 256, 0, stream>>>(tb, fb, count);
  edge_scan<<<BB, 256, 0, stream>>>(count, offs);
  edge_fill<<<(2 * MM + 255) / 256, 256, 0, stream>>>(tb, fb, offs, count, edges);

  for (int s = 0; s < MAXS; ++s) {
    for (int t = 0; t < TT; ++t) {
      const float* hin0 = (t == 0) ? Sh0 : Wh0w;
      const float* cin0 = (t == 0) ? Sc0 : Wc0;
      // layer 0: z = h@Wh0 + x_t@Wi0 + b0
      lstm_kernel<<<MM / 8, 128, 0, stream>>>(hin0, Wh0, embT + (size_t)t * MM * HH, Wi0,
                                              b0, cin0, Wc0, Wh0w, steps, s);
      const float* hin1 = (t == 0) ? Sh1 : Wh1w;
      const float* cin1 = (t == 0) ? Sc1 : Wc1;
      // layer 1: z = h0@Wi1 + h1@Wh1 + b1
      lstm_kernel<<<MM / 8, 128, 0, stream>>>(Wh0w, Wi1, hin1, Wh1,
                                              b1, cin1, Wc1, Wh1w, steps, s);
    }
    exit_restore<<<BB, 128, 0, stream>>>(Sc0, Sh0, Sc1, Sh1, Wc0, Wh0w, Wc1, Wh1w, exi, steps, s);
    branch_kernel<<<MM / 4, 256, 0, stream>>>(Wc0, Wh0w, Wc1, Wh1w, Wb, bb, ip, wt, wf, steps, s);
    agg_kernel<<<MM, 128, 0, stream>>>(offs, edges, wt, wf, Wc0, Wh0w, Wc1, Wh1w,
                                       Sc0, Sh0, Sc1, Sh1, ip, steps, s);
  }
  final_kernel<<<BB, 256, 0, stream>>>(Sc0, Sh0, Sc1, Sh1, exi, Wo, bo, out);
}

// Round 3
// 2872.392 us; speedup vs baseline: 1.4470x; 1.4470x over previous
//
#include <hip/hip_runtime.h>
#include <hip/hip_bf16.h>
#include <stdint.h>
#include <stddef.h>

static constexpr int BB = 16, NN = 256, TT = 4, HH = 128;
static constexpr int MM = BB * NN;     // 4096 rows
static constexpr int CC = 512;         // 4*H gate width
static constexpr int OUTV = 1000;
static constexpr int MAXS = 15;

__device__ __forceinline__ float sigmoidf(float x) { return 1.0f / (1.0f + __expf(-x)); }
__device__ __forceinline__ float fast_tanh(float x) { return 2.0f / (1.0f + __expf(-2.0f * x)) - 1.0f; }

// ---------------- setup kernels ----------------

__global__ void init_kernel(float* __restrict__ S, float* __restrict__ ip, int* __restrict__ count) {
  int tid = blockIdx.x * blockDim.x + threadIdx.x;
  int stride = gridDim.x * blockDim.x;
  int total = 4 * MM * HH;
  for (int i = tid; i < total; i += stride) S[i] = 0.0f;
  for (int i = tid; i < MM; i += stride) {
    ip[i] = ((i & (NN - 1)) == 0) ? 1.0f : 0.0f;
    count[i] = 0;
  }
}

// embT[t][m][j] = embed[data[m][t]][j]
__global__ void gather_emb(const int* __restrict__ data, const float* __restrict__ embed,
                           float* __restrict__ embT) {
  int tid = blockIdx.x * blockDim.x + threadIdx.x;
  int stride = gridDim.x * blockDim.x;
  const int total = TT * MM * HH;
  for (int i = tid; i < total; i += stride) {
    int j = i & (HH - 1);
    int m = (i >> 7) & (MM - 1);
    int t = i >> 19;  // i / (MM*HH), MM*HH = 2^19
    int tok = data[m * TT + t];
    embT[i] = embed[(size_t)tok * HH + j];
  }
}

// CSR build over the fixed branch graph: 2 edges per (b,n)
__global__ void edge_count(const int* __restrict__ tb, const int* __restrict__ fb,
                           int* __restrict__ count) {
  int e = blockIdx.x * blockDim.x + threadIdx.x;
  if (e >= 2 * MM) return;
  int b = e >> 9, r = e & 511, n = r >> 1, bit = r & 1;
  int tgt = bit ? fb[b * NN + n] : tb[b * NN + n];
  atomicAdd(&count[b * NN + tgt], 1);
}

__global__ void edge_scan(int* __restrict__ count, int* __restrict__ offs) {
  int b = blockIdx.x, tid = threadIdx.x;
  __shared__ int s[256];
  int v = count[b * NN + tid];
  s[tid] = v;
  __syncthreads();
  for (int off = 1; off < 256; off <<= 1) {
    int t = (tid >= off) ? s[tid - off] : 0;
    __syncthreads();
    s[tid] += t;
    __syncthreads();
  }
  offs[b * NN + tid] = b * 2 * NN + s[tid] - v;
  count[b * NN + tid] = 0;  // reuse as fill cursor
  if (b == 0 && tid == 0) offs[MM] = 2 * MM;
}

__global__ void edge_fill(const int* __restrict__ tb, const int* __restrict__ fb,
                          const int* __restrict__ offs, int* __restrict__ cursor,
                          int* __restrict__ edges) {
  int e = blockIdx.x * blockDim.x + threadIdx.x;
  if (e >= 2 * MM) return;
  int b = e >> 9, r = e & 511, n = r >> 1, bit = r & 1;
  int tgt = bit ? fb[b * NN + n] : tb[b * NN + n];
  int pos = offs[b * NN + tgt] + atomicAdd(&cursor[b * NN + tgt], 1);
  edges[pos] = (n << 1) | bit;
}

// ---------------- fused per-step kernel ----------------
// 8 rows/block, 256 threads (thread j -> gate cols j and j+256).
// All 4 tokens x 2 layers with states in LDS; branch softmax fused at the tail;
// exit-row restore applied at write-out (W buffers get pristine S at exit row).

__device__ __forceinline__ void mm8(const float A[8][HH], const float* __restrict__ Wg,
                                    int j, float za[8], float zb[8]) {
#pragma unroll 1
  for (int k4 = 0; k4 < HH / 4; ++k4) {
    float4 a[8];
#pragma unroll
    for (int r = 0; r < 8; ++r) a[r] = *(const float4*)&A[r][k4 * 4];
    float wa[4], wb[4];
#pragma unroll
    for (int kk = 0; kk < 4; ++kk) {
      wa[kk] = Wg[(size_t)(k4 * 4 + kk) * CC + j];
      wb[kk] = Wg[(size_t)(k4 * 4 + kk) * CC + j + 256];
    }
#pragma unroll
    for (int kk = 0; kk < 4; ++kk) {
#pragma unroll
      for (int r = 0; r < 8; ++r) {
        float av = ((const float*)&a[r])[kk];
        za[r] += av * wa[kk];
        zb[r] += av * wb[kk];
      }
    }
  }
}

__global__ __launch_bounds__(256) void step_kernel(
    const float* __restrict__ Sc0, const float* __restrict__ Sh0,
    const float* __restrict__ Sc1, const float* __restrict__ Sh1,
    float* __restrict__ Wc0, float* __restrict__ Wh0w,
    float* __restrict__ Wc1, float* __restrict__ Wh1w,
    const float* __restrict__ embT,
    const float* __restrict__ Wi0, const float* __restrict__ Wh0,
    const float* __restrict__ Wi1, const float* __restrict__ Wh1,
    const float* __restrict__ b0, const float* __restrict__ b1,
    const float* __restrict__ Wb, const float* __restrict__ bb,
    const float* __restrict__ ip, float* __restrict__ wt, float* __restrict__ wf,
    const int* __restrict__ exi, const int* __restrict__ steps, int step) {
  const int row0 = blockIdx.x * 8;
  const int b = row0 >> 8;
  if (step >= steps[b]) return;  // dead batch
  const int tid = threadIdx.x;
  const int j = tid;  // gate cols j, j+256

  __shared__ float h0[8][HH], c0[8][HH], h1[8][HH], c1[8][HH];
  __shared__ float xs[8][HH];
  __shared__ float zbuf[8][CC];

  // load states (4 elems per thread per buffer, coalesced)
#pragma unroll
  for (int e = 0; e < 4; ++e) {
    int flat = e * 256 + tid;
    int r = flat >> 7, cc2 = flat & 127;
    size_t g = (size_t)(row0 + r) * HH + cc2;
    c0[r][cc2] = Sc0[g];
    h0[r][cc2] = Sh0[g];
    c1[r][cc2] = Sc1[g];
    h1[r][cc2] = Sh1[g];
  }

  for (int t = 0; t < TT; ++t) {
    // stage x_t
#pragma unroll
    for (int e = 0; e < 4; ++e) {
      int flat = e * 256 + tid;
      int r = flat >> 7, cc2 = flat & 127;
      xs[r][cc2] = embT[(size_t)t * MM * HH + (size_t)(row0 + r) * HH + cc2];
    }
    __syncthreads();

    // ----- layer 0: z = x@Wi0 + h0@Wh0 + b0
    float za[8], zb[8];
    {
      float ba = b0[j], bbv = b0[j + 256];
#pragma unroll
      for (int r = 0; r < 8; ++r) { za[r] = ba; zb[r] = bbv; }
    }
    mm8(xs, Wi0, j, za, zb);
    mm8(h0, Wh0, j, za, zb);
#pragma unroll
    for (int r = 0; r < 8; ++r) { zbuf[r][j] = za[r]; zbuf[r][j + 256] = zb[r]; }
    __syncthreads();

    // gates 0 -> c0,h0 (in-LDS)
#pragma unroll
    for (int e = 0; e < 4; ++e) {
      int flat = e * 256 + tid;
      int r = flat >> 7, cc2 = flat & 127;
      float zi = zbuf[r][cc2], zf = zbuf[r][128 + cc2];
      float zg = zbuf[r][256 + cc2], zo = zbuf[r][384 + cc2];
      float c = c0[r][cc2];
      float cn = sigmoidf(zf) * c + sigmoidf(zi) * fast_tanh(zg);
      float hn = sigmoidf(zo) * fast_tanh(cn);
      c0[r][cc2] = cn;
      h0[r][cc2] = hn;
    }
    __syncthreads();

    // ----- layer 1: z = h0_new@Wi1 + h1@Wh1 + b1
    {
      float ba = b1[j], bbv = b1[j + 256];
#pragma unroll
      for (int r = 0; r < 8; ++r) { za[r] = ba; zb[r] = bbv; }
    }
    mm8(h0, Wi1, j, za, zb);
    mm8(h1, Wh1, j, za, zb);
#pragma unroll
    for (int r = 0; r < 8; ++r) { zbuf[r][j] = za[r]; zbuf[r][j + 256] = zb[r]; }
    __syncthreads();

    // gates 1 -> c1,h1
#pragma unroll
    for (int e = 0; e < 4; ++e) {
      int flat = e * 256 + tid;
      int r = flat >> 7, cc2 = flat & 127;
      float zi = zbuf[r][cc2], zf = zbuf[r][128 + cc2];
      float zg = zbuf[r][256 + cc2], zo = zbuf[r][384 + cc2];
      float c = c1[r][cc2];
      float cn = sigmoidf(zf) * c + sigmoidf(zi) * fast_tanh(zg);
      float hn = sigmoidf(zo) * fast_tanh(cn);
      c1[r][cc2] = cn;
      h1[r][cc2] = hn;
    }
    __syncthreads();
  }

  // ----- fused branch softmax (32 threads per row)
  {
    const int sub = tid & 31;
    const int r = tid >> 5;
    const int row = row0 + r;
    const int node = row & (NN - 1);
    const int exnode = exi[b];
    const bool isExit = (node == exnode);
    float z0 = 0.f, z1 = 0.f;
#pragma unroll
    for (int u = 0; u < 16; ++u) {
      int k = u * 32 + sub;
      float fk;
      if (isExit) {
        // exit row uses pristine pre-step state
        size_t g = (size_t)row * HH;
        if (k < 128)      fk = Sc0[g + k];
        else if (k < 256) fk = Sh0[g + k - 128];
        else if (k < 384) fk = Sc1[g + k - 256];
        else              fk = Sh1[g + k - 384];
      } else {
        if (k < 128)      fk = c0[r][k];
        else if (k < 256) fk = h0[r][k - 128];
        else if (k < 384) fk = c1[r][k - 256];
        else              fk = h1[r][k - 384];
      }
      z0 += fk * Wb[2 * k];
      z1 += fk * Wb[2 * k + 1];
    }
#pragma unroll
    for (int off = 16; off > 0; off >>= 1) {
      z0 += __shfl_xor(z0, off);
      z1 += __shfl_xor(z1, off);
    }
    if (sub == 0) {
      z0 += bb[0]; z1 += bb[1];
      float m = fmaxf(z0, z1);
      float e0 = __expf(z0 - m), e1 = __expf(z1 - m);
      float inv = 1.0f / (e0 + e1);
      float ipv = ip[row];
      wt[row] = e0 * inv * ipv;
      wf[row] = e1 * inv * ipv;
    }
  }

  // ----- write-out working state; exit row restored from pristine S
  {
    const int exnode = exi[b];
#pragma unroll
    for (int e = 0; e < 4; ++e) {
      int flat = e * 256 + tid;
      int r = flat >> 7, cc2 = flat & 127;
      int row = row0 + r;
      bool ex = ((row & (NN - 1)) == exnode);
      size_t g = (size_t)row * HH + cc2;
      Wc0[g]  = ex ? Sc0[g] : c0[r][cc2];
      Wh0w[g] = ex ? Sh0[g] : h0[r][cc2];
      Wc1[g]  = ex ? Sc1[g] : c1[r][cc2];
      Wh1w[g] = ex ? Sh1[g] : h1[r][cc2];
    }
  }
}

// CSR gather aggregation: S[b,v,:] = (sum_e w_e * W[b,src_e,:]) / (wsum+1e-7); ip update.
__global__ void agg_kernel(const int* __restrict__ offs, const int* __restrict__ edges,
                           const float* __restrict__ wt, const float* __restrict__ wf,
                           const float* __restrict__ Wc0, const float* __restrict__ Wh0,
                           const float* __restrict__ Wc1, const float* __restrict__ Wh1,
                           float* __restrict__ Sc0, float* __restrict__ Sh0,
                           float* __restrict__ Sc1, float* __restrict__ Sh1,
                           float* __restrict__ ip,
                           const int* __restrict__ steps, int step) {
  const int idx = blockIdx.x;  // b*256 + v
  const int b = idx >> 8;
  if (step >= steps[b]) return;
  const int j = threadIdx.x;
  const int beg = offs[idx], end = offs[idx + 1];
  float ac0 = 0.f, ah0 = 0.f, ac1 = 0.f, ah1 = 0.f, wsum = 0.f;
  for (int e = beg; e < end; ++e) {
    int rec = edges[e];
    int src = (b << 8) + (rec >> 1);
    float w = (rec & 1) ? wf[src] : wt[src];
    wsum += w;
    size_t sb = (size_t)src * HH + j;
    ac0 += w * Wc0[sb]; ah0 += w * Wh0[sb];
    ac1 += w * Wc1[sb]; ah1 += w * Wh1[sb];
  }
  float inv = 1.0f / (wsum + 1e-7f);
  size_t db = (size_t)idx * HH + j;
  Sc0[db] = ac0 * inv; Sh0[db] = ah0 * inv;
  Sc1[db] = ac1 * inv; Sh1[db] = ah1 * inv;
  if (j == 0) ip[idx] = wsum;
}

// logits: 128 blocks (16 batches x 8 col-tiles of 125), 128 threads
__global__ void final_kernel(const float* __restrict__ Sc0, const float* __restrict__ Sh0,
                             const float* __restrict__ Sc1, const float* __restrict__ Sh1,
                             const int* __restrict__ exi, const float* __restrict__ Wo,
                             const float* __restrict__ bo, float* __restrict__ out) {
  const int b = blockIdx.x >> 3;
  const int vt = blockIdx.x & 7;
  const int tid = threadIdx.x;  // 128
  __shared__ float f[512];
  int row = b * NN + exi[b];
#pragma unroll
  for (int e = 0; e < 4; ++e) {
    int i = e * 128 + tid;
    int seg = i >> 7, k = i & 127;
    const float* S = (seg == 0) ? Sc0 : (seg == 1) ? Sh0 : (seg == 2) ? Sc1 : Sh1;
    f[i] = S[(size_t)row * HH + k];
  }
  __syncthreads();
  int v0 = vt * 125;
  for (int v = v0 + tid; v < v0 + 125; v += 128) {
    float acc = bo[v];
#pragma unroll 4
    for (int k = 0; k < 512; ++k) acc += f[k] * Wo[(size_t)k * OUTV + v];
    out[b * OUTV + v] = acc;
  }
}

// distinct failure signature if workspace is too small: out := 0 -> err == ref absmax
__global__ void zero_out_kernel(float* __restrict__ out, int n) {
  int i = blockIdx.x * blockDim.x + threadIdx.x;
  if (i < n) out[i] = 0.0f;
}

// ---------------- host orchestration ----------------

extern "C" void kernel_launch(void* const* d_in, const int* in_sizes, int n_in,
                              void* d_out, int out_size, void* d_ws, size_t ws_size,
                              hipStream_t stream) {
  const int* data = (const int*)d_in[0];
  const int* tb   = (const int*)d_in[1];
  const int* fb   = (const int*)d_in[2];
  const int* exi  = (const int*)d_in[3];
  const int* steps = (const int*)d_in[4];
  const float* embed = (const float*)d_in[5];
  const float* Wi = (const float*)d_in[6];   // (L,H,4H)
  const float* Wh = (const float*)d_in[7];   // (L,H,4H)
  const float* bl = (const float*)d_in[8];   // (L,4H)
  const float* Wb = (const float*)d_in[9];   // (2LH,2)
  const float* bb = (const float*)d_in[10];  // (2,)
  const float* Wo = (const float*)d_in[11];  // (2LH,OUT)
  const float* bo = (const float*)d_in[12];  // (OUT,)
  float* out = (float*)d_out;

  const float* Wi0 = Wi;
  const float* Wi1 = Wi + HH * CC;
  const float* Wh0 = Wh;
  const float* Wh1 = Wh + HH * CC;
  const float* b0 = bl;
  const float* b1 = bl + CC;

  float* ws = (float*)d_ws;
  size_t off = 0;
  float* embT = ws + off; off += (size_t)TT * MM * HH;
  float* Sc0 = ws + off;  off += (size_t)MM * HH;  // 4 contiguous state bufs
  float* Sh0 = ws + off;  off += (size_t)MM * HH;
  float* Sc1 = ws + off;  off += (size_t)MM * HH;
  float* Sh1 = ws + off;  off += (size_t)MM * HH;
  float* Wc0 = ws + off;  off += (size_t)MM * HH;  // 4 working bufs
  float* Wh0w = ws + off; off += (size_t)MM * HH;
  float* Wc1 = ws + off;  off += (size_t)MM * HH;
  float* Wh1w = ws + off; off += (size_t)MM * HH;
  float* ip = ws + off;   off += MM;
  float* wt = ws + off;   off += MM;
  float* wf = ws + off;   off += MM;
  int* count = (int*)(ws + off); off += MM;
  int* offs  = (int*)(ws + off); off += MM + 4;
  int* edges = (int*)(ws + off); off += 2 * MM;
  (void)in_sizes; (void)n_in; (void)out_size;

  if (ws_size < off * sizeof(float)) {
    zero_out_kernel<<<(BB * OUTV + 255) / 256, 256, 0, stream>>>(out, BB * OUTV);
    return;
  }

  init_kernel<<<256, 256, 0, stream>>>(Sc0, ip, count);
  gather_emb<<<512, 256, 0, stream>>>(data, embed, embT);
  edge_count<<<(2 * MM + 255) / 256, 256, 0, stream>>>(tb, fb, count);
  edge_scan<<<BB, 256, 0, stream>>>(count, offs);
  edge_fill<<<(2 * MM + 255) / 256, 256, 0, stream>>>(tb, fb, offs, count, edges);

  for (int s = 0; s < MAXS; ++s) {
    step_kernel<<<MM / 8, 256, 0, stream>>>(
        Sc0, Sh0, Sc1, Sh1, Wc0, Wh0w, Wc1, Wh1w, embT,
        Wi0, Wh0, Wi1, Wh1, b0, b1, Wb, bb, ip, wt, wf, exi, steps, s);
    agg_kernel<<<MM, 128, 0, stream>>>(offs, edges, wt, wf, Wc0, Wh0w, Wc1, Wh1w,
                                       Sc0, Sh0, Sc1, Sh1, ip, steps, s);
  }
  final_kernel<<<BB * 8, 128, 0, stream>>>(Sc0, Sh0, Sc1, Sh1, exi, Wo, bo, out);
}

// Round 4
// 981.577 us; speedup vs baseline: 4.2343x; 2.9263x over previous
//
#include <hip/hip_runtime.h>
#include <hip/hip_bf16.h>
#include <stdint.h>
#include <stddef.h>

static constexpr int BB = 16, NN = 256, TT = 4, HH = 128;
static constexpr int MM = BB * NN;     // 4096 rows
static constexpr int CC = 512;         // 4*H gate width
static constexpr int OUTV = 1000;
static constexpr int MAXS = 15;
static constexpr int ZP = 516;         // zbuf row pitch (f32)
static constexpr int SP = 132;         // state row pitch (f32)

typedef float f32x4 __attribute__((ext_vector_type(4)));
typedef short s16x8 __attribute__((ext_vector_type(8)));

__device__ __forceinline__ float sigf(float x) { return 1.0f / (1.0f + __expf(-x)); }
__device__ __forceinline__ float tanhr(float x) { return 2.0f / (1.0f + __expf(-2.0f * x)) - 1.0f; }
__device__ __forceinline__ unsigned int pack2(float a, float b) {
  unsigned short ua = __builtin_bit_cast(unsigned short, __float2bfloat16(a));
  unsigned short ub = __builtin_bit_cast(unsigned short, __float2bfloat16(b));
  return (unsigned int)ua | ((unsigned int)ub << 16);
}

// ---------------- setup kernels ----------------

__global__ void init_kernel(float* __restrict__ S, float* __restrict__ ip, int* __restrict__ count) {
  int tid = blockIdx.x * blockDim.x + threadIdx.x;
  int stride = gridDim.x * blockDim.x;
  int total = 4 * MM * HH;
  for (int i = tid; i < total; i += stride) S[i] = 0.0f;
  for (int i = tid; i < MM; i += stride) {
    ip[i] = ((i & (NN - 1)) == 0) ? 1.0f : 0.0f;
    count[i] = 0;
  }
}

// swizzle one 128x512 f32 weight matrix into bf16 B-fragment order:
// out[((ct*4+kb)*64 + q*16+n)*8 + j] = W[kb*32+q*8+j][ct*16+n]
__global__ void swz_kernel(const float* __restrict__ W, unsigned short* __restrict__ out) {
  int i = blockIdx.x * 256 + threadIdx.x;  // 0..65535
  int j = i & 7, ln = (i >> 3) & 63, kb = (i >> 9) & 3, ct = i >> 11;
  int n = ln & 15, q = ln >> 4;
  int k = kb * 32 + q * 8 + j;
  int col = ct * 16 + n;
  out[i] = __builtin_bit_cast(unsigned short, __float2bfloat16(W[k * CC + col]));
}

// tab[v][col] = embed[v] @ Wi0 + b0   (f32, one-time; rows >=1000 clamped/unused)
__global__ void xw0tab_kernel(const float* __restrict__ embed, const float* __restrict__ Wi0,
                              const float* __restrict__ b0, float* __restrict__ tab) {
  const int v0 = blockIdx.x * 8;
  const int j = threadIdx.x;  // 256
  __shared__ float A[8][HH];
  for (int s = j; s < 8 * HH; s += 256) {
    int r = s >> 7, k = s & 127;
    int v = v0 + r; if (v >= OUTV) v = OUTV - 1;
    A[r][k] = embed[(size_t)v * HH + k];
  }
  __syncthreads();
  float za[8], zb[8];
  {
    float ba = b0[j], bbv = b0[j + 256];
#pragma unroll
    for (int r = 0; r < 8; ++r) { za[r] = ba; zb[r] = bbv; }
  }
#pragma unroll 4
  for (int k = 0; k < HH; ++k) {
    float wa = Wi0[k * CC + j], wb = Wi0[k * CC + j + 256];
#pragma unroll
    for (int r = 0; r < 8; ++r) { za[r] += A[r][k] * wa; zb[r] += A[r][k] * wb; }
  }
#pragma unroll
  for (int r = 0; r < 8; ++r) {
    tab[(size_t)(v0 + r) * CC + j] = za[r];
    tab[(size_t)(v0 + r) * CC + j + 256] = zb[r];
  }
}

// CSR build over the fixed branch graph: 2 edges per (b,n)
__global__ void edge_count(const int* __restrict__ tb, const int* __restrict__ fb,
                           int* __restrict__ count) {
  int e = blockIdx.x * blockDim.x + threadIdx.x;
  if (e >= 2 * MM) return;
  int b = e >> 9, r = e & 511, n = r >> 1, bit = r & 1;
  int tgt = bit ? fb[b * NN + n] : tb[b * NN + n];
  atomicAdd(&count[b * NN + tgt], 1);
}

__global__ void edge_scan(int* __restrict__ count, int* __restrict__ offs) {
  int b = blockIdx.x, tid = threadIdx.x;
  __shared__ int s[256];
  int v = count[b * NN + tid];
  s[tid] = v;
  __syncthreads();
  for (int off = 1; off < 256; off <<= 1) {
    int t = (tid >= off) ? s[tid - off] : 0;
    __syncthreads();
    s[tid] += t;
    __syncthreads();
  }
  offs[b * NN + tid] = b * 2 * NN + s[tid] - v;
  count[b * NN + tid] = 0;  // reuse as fill cursor
  if (b == 0 && tid == 0) offs[MM] = 2 * MM;
}

__global__ void edge_fill(const int* __restrict__ tb, const int* __restrict__ fb,
                          const int* __restrict__ offs, int* __restrict__ cursor,
                          int* __restrict__ edges) {
  int e = blockIdx.x * blockDim.x + threadIdx.x;
  if (e >= 2 * MM) return;
  int b = e >> 9, r = e & 511, n = r >> 1, bit = r & 1;
  int tgt = bit ? fb[b * NN + n] : tb[b * NN + n];
  int pos = offs[b * NN + tgt] + atomicAdd(&cursor[b * NN + tgt], 1);
  edges[pos] = (n << 1) | bit;
}

// ---------------- fused MFMA per-step kernel ----------------
// 16 rows/block, 256 blocks, 256 threads = 4 waves; wave w owns z-col tiles w*8..w*8+7.
// MFMA 16x16x32 bf16; Wh0/Wh1 persistent in VGPRs; Wi1 streamed; x@Wi0+b0 from vocab table.

__global__ __launch_bounds__(256, 1) void step_kernel(
    const float* __restrict__ Sc0, const float* __restrict__ Sh0,
    const float* __restrict__ Sc1, const float* __restrict__ Sh1,
    float* __restrict__ Wc0, float* __restrict__ Wh0w,
    float* __restrict__ Wc1, float* __restrict__ Wh1w,
    const float* __restrict__ tab,
    const unsigned short* __restrict__ swzWh0, const unsigned short* __restrict__ swzWi1,
    const unsigned short* __restrict__ swzWh1, const float* __restrict__ b1,
    const float* __restrict__ Wb, const float* __restrict__ bb,
    const float* __restrict__ ip, float* __restrict__ wt, float* __restrict__ wf,
    const int* __restrict__ data, const int* __restrict__ exi,
    const int* __restrict__ steps, int step) {
  const int row0 = blockIdx.x * 16;
  const int b = row0 >> 8;
  if (step >= steps[b]) return;
  const int tid = threadIdx.x;
  const int w = tid >> 6;
  const int lane = tid & 63;
  const int n16 = lane & 15, qq = lane >> 4;        // MFMA B/D lane decomposition
  const int gm = tid & 15, gq = (tid >> 4) & 3, ge = tid >> 6;  // gate-phase mapping

  __shared__ float zbuf[16 * ZP];
  __shared__ float c0L[16 * SP], h0L[16 * SP], c1L[16 * SP], h1L[16 * SP];
  __shared__ unsigned int hA0u[1024], hA1u[1024];
  __shared__ int toks[64];

  // persistent B fragments (Wh0, Wh1): 8 tiles x 4 kb x 16B = 256 VGPRs
  s16x8 B0[8][4], B1[8][4];
  const s16x8* pWh0 = (const s16x8*)swzWh0;
  const s16x8* pWh1 = (const s16x8*)swzWh1;
  const s16x8* pWi1 = (const s16x8*)swzWi1;
#pragma unroll
  for (int ct = 0; ct < 8; ++ct) {
#pragma unroll
    for (int kb = 0; kb < 4; ++kb) {
      int fi = ((w * 8 + ct) * 4 + kb) * 64 + lane;
      B0[ct][kb] = pWh0[fi];
      B1[ct][kb] = pWh1[fi];
    }
  }
  float b1v[8];
#pragma unroll
  for (int ct = 0; ct < 8; ++ct) b1v[ct] = b1[(w * 8 + ct) * 16 + n16];

  // stage states into LDS (f32)
  for (int s = tid; s < 16 * HH; s += 256) {
    int m = s >> 7, k = s & 127;
    size_t g = (size_t)(row0 + m) * HH + k;
    c0L[m * SP + k] = Sc0[g];
    h0L[m * SP + k] = Sh0[g];
    c1L[m * SP + k] = Sc1[g];
    h1L[m * SP + k] = Sh1[g];
  }
  if (tid < 64) toks[tid] = data[(row0 + (tid >> 2)) * TT + (tid & 3)];
  __syncthreads();

  // build bf16 A-operand buffers (fragment order) from staged h
#pragma unroll
  for (int kb = 0; kb < 4; ++kb) {
    int k = kb * 32 + gq * 8 + ge * 2;
    int du = (kb * 64 + gq * 16 + gm) * 4 + ge;
    hA0u[du] = pack2(h0L[gm * SP + k], h0L[gm * SP + k + 1]);
    hA1u[du] = pack2(h1L[gm * SP + k], h1L[gm * SP + k + 1]);
  }
  __syncthreads();

  const s16x8* hA0v = (const s16x8*)hA0u;
  const s16x8* hA1v = (const s16x8*)hA1u;

  for (int t = 0; t < TT; ++t) {
    // read old-h fragments before this token's gates overwrite them
    s16x8 a0[4], a1b[4];
#pragma unroll
    for (int kb = 0; kb < 4; ++kb) { a0[kb] = hA0v[kb * 64 + lane]; a1b[kb] = hA1v[kb * 64 + lane]; }
    // stage zbuf <- XW0 table rows (z-init for layer 0, includes b0)
    for (int s = tid; s < 16 * CC; s += 256) {
      int m = s >> 9, col = s & 511;
      zbuf[m * ZP + col] = tab[(size_t)toks[m * 4 + t] * CC + col];
    }
    __syncthreads();

    // ----- layer 0 MFMA: z += h0 @ Wh0
#pragma unroll
    for (int ct = 0; ct < 8; ++ct) {
      int colz = (w * 8 + ct) * 16 + n16;
      f32x4 d;
#pragma unroll
      for (int r = 0; r < 4; ++r) d[r] = zbuf[(qq * 4 + r) * ZP + colz];
#pragma unroll
      for (int kb = 0; kb < 4; ++kb)
        d = __builtin_amdgcn_mfma_f32_16x16x32_bf16(a0[kb], B0[ct][kb], d, 0, 0, 0);
#pragma unroll
      for (int r = 0; r < 4; ++r) zbuf[(qq * 4 + r) * ZP + colz] = d[r];
    }
    __syncthreads();

    // ----- gates 0 -> c0, h0 (f32 LDS) + hA0 (bf16 frags)
#pragma unroll
    for (int kb = 0; kb < 4; ++kb) {
      int k = kb * 32 + gq * 8 + ge * 2;
      float hres[2];
#pragma unroll
      for (int dj = 0; dj < 2; ++dj) {
        int kk = k + dj;
        float zi = zbuf[gm * ZP + kk];
        float zf = zbuf[gm * ZP + 128 + kk];
        float zg = zbuf[gm * ZP + 256 + kk];
        float zo = zbuf[gm * ZP + 384 + kk];
        float c = c0L[gm * SP + kk];
        float cn = sigf(zf) * c + sigf(zi) * tanhr(zg);
        float hn = sigf(zo) * tanhr(cn);
        c0L[gm * SP + kk] = cn;
        h0L[gm * SP + kk] = hn;
        hres[dj] = hn;
      }
      hA0u[(kb * 64 + gq * 16 + gm) * 4 + ge] = pack2(hres[0], hres[1]);
    }
    __syncthreads();

    // ----- layer 1 MFMA: z = b1 + h0new @ Wi1 + h1 @ Wh1
    s16x8 a1a[4];
#pragma unroll
    for (int kb = 0; kb < 4; ++kb) a1a[kb] = hA0v[kb * 64 + lane];
    s16x8 wi[4], win[4];
#pragma unroll
    for (int kb = 0; kb < 4; ++kb) wi[kb] = pWi1[((w * 8) * 4 + kb) * 64 + lane];
#pragma unroll
    for (int ct = 0; ct < 8; ++ct) {
      if (ct < 7) {
#pragma unroll
        for (int kb = 0; kb < 4; ++kb) win[kb] = pWi1[((w * 8 + ct + 1) * 4 + kb) * 64 + lane];
      }
      int colz = (w * 8 + ct) * 16 + n16;
      f32x4 d = { b1v[ct], b1v[ct], b1v[ct], b1v[ct] };
#pragma unroll
      for (int kb = 0; kb < 4; ++kb)
        d = __builtin_amdgcn_mfma_f32_16x16x32_bf16(a1a[kb], wi[kb], d, 0, 0, 0);
#pragma unroll
      for (int kb = 0; kb < 4; ++kb)
        d = __builtin_amdgcn_mfma_f32_16x16x32_bf16(a1b[kb], B1[ct][kb], d, 0, 0, 0);
#pragma unroll
      for (int r = 0; r < 4; ++r) zbuf[(qq * 4 + r) * ZP + colz] = d[r];
#pragma unroll
      for (int kb = 0; kb < 4; ++kb) wi[kb] = win[kb];
    }
    __syncthreads();

    // ----- gates 1 -> c1, h1 + hA1
#pragma unroll
    for (int kb = 0; kb < 4; ++kb) {
      int k = kb * 32 + gq * 8 + ge * 2;
      float hres[2];
#pragma unroll
      for (int dj = 0; dj < 2; ++dj) {
        int kk = k + dj;
        float zi = zbuf[gm * ZP + kk];
        float zf = zbuf[gm * ZP + 128 + kk];
        float zg = zbuf[gm * ZP + 256 + kk];
        float zo = zbuf[gm * ZP + 384 + kk];
        float c = c1L[gm * SP + kk];
        float cn = sigf(zf) * c + sigf(zi) * tanhr(zg);
        float hn = sigf(zo) * tanhr(cn);
        c1L[gm * SP + kk] = cn;
        h1L[gm * SP + kk] = hn;
        hres[dj] = hn;
      }
      hA1u[(kb * 64 + gq * 16 + gm) * 4 + ge] = pack2(hres[0], hres[1]);
    }
    __syncthreads();
  }

  // ----- fused branch softmax (16 threads per row); exit row uses pristine S
  {
    const int m = tid >> 4, sub = tid & 15;
    const int row = row0 + m;
    const int exnode = exi[b];
    const bool isExit = ((row & (NN - 1)) == exnode);
    float z0 = 0.f, z1 = 0.f;
#pragma unroll
    for (int u = 0; u < 32; ++u) {
      int k = u * 16 + sub;
      int seg = k >> 7, kk = k & 127;
      float fk;
      if (isExit) {
        size_t g = (size_t)row * HH + kk;
        fk = (seg == 0) ? Sc0[g] : (seg == 1) ? Sh0[g] : (seg == 2) ? Sc1[g] : Sh1[g];
      } else {
        fk = (seg == 0) ? c0L[m * SP + kk] : (seg == 1) ? h0L[m * SP + kk]
           : (seg == 2) ? c1L[m * SP + kk] : h1L[m * SP + kk];
      }
      z0 += fk * Wb[2 * k];
      z1 += fk * Wb[2 * k + 1];
    }
#pragma unroll
    for (int off = 8; off >= 1; off >>= 1) {
      z0 += __shfl_xor(z0, off);
      z1 += __shfl_xor(z1, off);
    }
    if (sub == 0) {
      z0 += bb[0]; z1 += bb[1];
      float mx = fmaxf(z0, z1);
      float e0 = __expf(z0 - mx), e1 = __expf(z1 - mx);
      float inv = 1.0f / (e0 + e1);
      float ipv = ip[row];
      wt[row] = e0 * inv * ipv;
      wf[row] = e1 * inv * ipv;
    }
  }

  // ----- writeout working state; exit row restored from pristine S
  {
    const int exnode = exi[b];
    for (int s = tid; s < 16 * HH; s += 256) {
      int m = s >> 7, k = s & 127;
      int row = row0 + m;
      bool ex = ((row & (NN - 1)) == exnode);
      size_t g = (size_t)row * HH + k;
      Wc0[g]  = ex ? Sc0[g] : c0L[m * SP + k];
      Wh0w[g] = ex ? Sh0[g] : h0L[m * SP + k];
      Wc1[g]  = ex ? Sc1[g] : c1L[m * SP + k];
      Wh1w[g] = ex ? Sh1[g] : h1L[m * SP + k];
    }
  }
}

// CSR gather aggregation, float4: 8 nodes/block, 32 lanes/node.
__global__ void agg_kernel(const int* __restrict__ offs, const int* __restrict__ edges,
                           const float* __restrict__ wt, const float* __restrict__ wf,
                           const float* __restrict__ Wc0, const float* __restrict__ Wh0,
                           const float* __restrict__ Wc1, const float* __restrict__ Wh1,
                           float* __restrict__ Sc0, float* __restrict__ Sh0,
                           float* __restrict__ Sc1, float* __restrict__ Sh1,
                           float* __restrict__ ip,
                           const int* __restrict__ steps, int step) {
  const int idx0 = blockIdx.x * 8;
  const int b = idx0 >> 8;
  if (step >= steps[b]) return;
  const int node = idx0 + (threadIdx.x >> 5);
  const int l = threadIdx.x & 31;
  const int beg = offs[node], end = offs[node + 1];
  float ac0[4] = {0,0,0,0}, ah0[4] = {0,0,0,0}, ac1[4] = {0,0,0,0}, ah1[4] = {0,0,0,0};
  float wsum = 0.f;
  for (int e = beg; e < end; ++e) {
    int rec = edges[e];
    int src = (b << 8) + (rec >> 1);
    float wv = (rec & 1) ? wf[src] : wt[src];
    wsum += wv;
    const float4 x0 = ((const float4*)Wc0)[src * 32 + l];
    const float4 x1 = ((const float4*)Wh0)[src * 32 + l];
    const float4 x2 = ((const float4*)Wc1)[src * 32 + l];
    const float4 x3 = ((const float4*)Wh1)[src * 32 + l];
    ac0[0] += wv * x0.x; ac0[1] += wv * x0.y; ac0[2] += wv * x0.z; ac0[3] += wv * x0.w;
    ah0[0] += wv * x1.x; ah0[1] += wv * x1.y; ah0[2] += wv * x1.z; ah0[3] += wv * x1.w;
    ac1[0] += wv * x2.x; ac1[1] += wv * x2.y; ac1[2] += wv * x2.z; ac1[3] += wv * x2.w;
    ah1[0] += wv * x3.x; ah1[1] += wv * x3.y; ah1[2] += wv * x3.z; ah1[3] += wv * x3.w;
  }
  float inv = 1.0f / (wsum + 1e-7f);
  float4 o;
  o.x = ac0[0]*inv; o.y = ac0[1]*inv; o.z = ac0[2]*inv; o.w = ac0[3]*inv;
  ((float4*)Sc0)[node * 32 + l] = o;
  o.x = ah0[0]*inv; o.y = ah0[1]*inv; o.z = ah0[2]*inv; o.w = ah0[3]*inv;
  ((float4*)Sh0)[node * 32 + l] = o;
  o.x = ac1[0]*inv; o.y = ac1[1]*inv; o.z = ac1[2]*inv; o.w = ac1[3]*inv;
  ((float4*)Sc1)[node * 32 + l] = o;
  o.x = ah1[0]*inv; o.y = ah1[1]*inv; o.z = ah1[2]*inv; o.w = ah1[3]*inv;
  ((float4*)Sh1)[node * 32 + l] = o;
  if (l == 0) ip[node] = wsum;
}

// logits: 128 blocks (16 batches x 8 col-tiles of 125), 128 threads
__global__ void final_kernel(const float* __restrict__ Sc0, const float* __restrict__ Sh0,
                             const float* __restrict__ Sc1, const float* __restrict__ Sh1,
                             const int* __restrict__ exi, const float* __restrict__ Wo,
                             const float* __restrict__ bo, float* __restrict__ out) {
  const int b = blockIdx.x >> 3;
  const int vt = blockIdx.x & 7;
  const int tid = threadIdx.x;  // 128
  __shared__ float f[512];
  int row = b * NN + exi[b];
#pragma unroll
  for (int e = 0; e < 4; ++e) {
    int i = e * 128 + tid;
    int seg = i >> 7, k = i & 127;
    const float* S = (seg == 0) ? Sc0 : (seg == 1) ? Sh0 : (seg == 2) ? Sc1 : Sh1;
    f[i] = S[(size_t)row * HH + k];
  }
  __syncthreads();
  int v0 = vt * 125;
  for (int v = v0 + tid; v < v0 + 125; v += 128) {
    float acc = bo[v];
#pragma unroll 4
    for (int k = 0; k < 512; ++k) acc += f[k] * Wo[(size_t)k * OUTV + v];
    out[b * OUTV + v] = acc;
  }
}

// distinct failure signature if workspace too small: out := 0 -> err == ref absmax
__global__ void zero_out_kernel(float* __restrict__ out, int n) {
  int i = blockIdx.x * blockDim.x + threadIdx.x;
  if (i < n) out[i] = 0.0f;
}

// ---------------- host orchestration ----------------

extern "C" void kernel_launch(void* const* d_in, const int* in_sizes, int n_in,
                              void* d_out, int out_size, void* d_ws, size_t ws_size,
                              hipStream_t stream) {
  const int* data = (const int*)d_in[0];
  const int* tb   = (const int*)d_in[1];
  const int* fb   = (const int*)d_in[2];
  const int* exi  = (const int*)d_in[3];
  const int* steps = (const int*)d_in[4];
  const float* embed = (const float*)d_in[5];
  const float* Wi = (const float*)d_in[6];   // (L,H,4H)
  const float* Wh = (const float*)d_in[7];   // (L,H,4H)
  const float* bl = (const float*)d_in[8];   // (L,4H)
  const float* Wb = (const float*)d_in[9];   // (2LH,2)
  const float* bb = (const float*)d_in[10];  // (2,)
  const float* Wo = (const float*)d_in[11];  // (2LH,OUT)
  const float* bo = (const float*)d_in[12];  // (OUT,)
  float* out = (float*)d_out;

  const float* Wi0 = Wi;
  const float* Wi1 = Wi + HH * CC;
  const float* Wh0 = Wh;
  const float* Wh1 = Wh + HH * CC;
  const float* b0 = bl;
  const float* b1 = bl + CC;

  float* ws = (float*)d_ws;
  size_t off = 0;
  float* tab = ws + off;  off += (size_t)1024 * CC;        // 2 MB
  float* Sc0 = ws + off;  off += (size_t)MM * HH;
  float* Sh0 = ws + off;  off += (size_t)MM * HH;
  float* Sc1 = ws + off;  off += (size_t)MM * HH;
  float* Sh1 = ws + off;  off += (size_t)MM * HH;
  float* Wc0 = ws + off;  off += (size_t)MM * HH;
  float* Wh0w = ws + off; off += (size_t)MM * HH;
  float* Wc1 = ws + off;  off += (size_t)MM * HH;
  float* Wh1w = ws + off; off += (size_t)MM * HH;
  unsigned short* swzWh0 = (unsigned short*)(ws + off); off += (size_t)HH * CC / 2;
  unsigned short* swzWi1 = (unsigned short*)(ws + off); off += (size_t)HH * CC / 2;
  unsigned short* swzWh1 = (unsigned short*)(ws + off); off += (size_t)HH * CC / 2;
  float* ip = ws + off;   off += MM;
  float* wt = ws + off;   off += MM;
  float* wf = ws + off;   off += MM;
  int* count = (int*)(ws + off); off += MM;
  int* offs  = (int*)(ws + off); off += MM + 16;
  int* edges = (int*)(ws + off); off += 2 * MM;
  (void)in_sizes; (void)n_in; (void)out_size;

  if (ws_size < off * sizeof(float)) {
    zero_out_kernel<<<(BB * OUTV + 255) / 256, 256, 0, stream>>>(out, BB * OUTV);
    return;
  }

  init_kernel<<<256, 256, 0, stream>>>(Sc0, ip, count);
  swz_kernel<<<256, 256, 0, stream>>>(Wh0, swzWh0);
  swz_kernel<<<256, 256, 0, stream>>>(Wi1, swzWi1);
  swz_kernel<<<256, 256, 0, stream>>>(Wh1, swzWh1);
  xw0tab_kernel<<<128, 256, 0, stream>>>(embed, Wi0, b0, tab);
  edge_count<<<(2 * MM + 255) / 256, 256, 0, stream>>>(tb, fb, count);
  edge_scan<<<BB, 256, 0, stream>>>(count, offs);
  edge_fill<<<(2 * MM + 255) / 256, 256, 0, stream>>>(tb, fb, offs, count, edges);

  for (int s = 0; s < MAXS; ++s) {
    step_kernel<<<MM / 16, 256, 0, stream>>>(
        Sc0, Sh0, Sc1, Sh1, Wc0, Wh0w, Wc1, Wh1w, tab,
        swzWh0, swzWi1, swzWh1, b1, Wb, bb, ip, wt, wf, data, exi, steps, s);
    agg_kernel<<<MM / 8, 256, 0, stream>>>(offs, edges, wt, wf, Wc0, Wh0w, Wc1, Wh1w,
                                           Sc0, Sh0, Sc1, Sh1, ip, steps, s);
  }
  final_kernel<<<BB * 8, 128, 0, stream>>>(Sc0, Sh0, Sc1, Sh1, exi, Wo, bo, out);
}

// Round 5
// 684.123 us; speedup vs baseline: 6.0753x; 1.4348x over previous
//
#include <hip/hip_runtime.h>
#include <hip/hip_bf16.h>
#include <stdint.h>
#include <stddef.h>

static constexpr int BB = 16, NN = 256, TT = 4, HH = 128;
static constexpr int MM = BB * NN;     // 4096 rows
static constexpr int CC = 512;         // 4*H gate width
static constexpr int OUTV = 1000;
static constexpr int MAXS = 15;
static constexpr int ZP = 516;         // zbuf row pitch (f32)
static constexpr int SP = 132;         // state row pitch (f32)

typedef float f32x4 __attribute__((ext_vector_type(4)));
typedef short s16x8 __attribute__((ext_vector_type(8)));

__device__ __forceinline__ float sigf(float x) { return 1.0f / (1.0f + __expf(-x)); }
__device__ __forceinline__ float tanhr(float x) { return 2.0f / (1.0f + __expf(-2.0f * x)) - 1.0f; }
__device__ __forceinline__ unsigned int pack2(float a, float b) {
  unsigned short ua = __builtin_bit_cast(unsigned short, __float2bfloat16(a));
  unsigned short ub = __builtin_bit_cast(unsigned short, __float2bfloat16(b));
  return (unsigned int)ua | ((unsigned int)ub << 16);
}

// ---------------- setup kernels ----------------

__global__ void init_kernel(float* __restrict__ S, float* __restrict__ ip, int* __restrict__ count) {
  int tid = blockIdx.x * blockDim.x + threadIdx.x;
  int stride = gridDim.x * blockDim.x;
  int total = 4 * MM * HH;
  for (int i = tid; i < total; i += stride) S[i] = 0.0f;
  for (int i = tid; i < MM; i += stride) {
    ip[i] = ((i & (NN - 1)) == 0) ? 1.0f : 0.0f;
    count[i] = 0;
  }
}

// swizzle one 128x512 f32 weight matrix into bf16 B-fragment order:
// out[((ct*4+kb)*64 + q*16+n)*8 + j] = W[kb*32+q*8+j][ct*16+n]
__global__ void swz_kernel(const float* __restrict__ W, unsigned short* __restrict__ out) {
  int i = blockIdx.x * 256 + threadIdx.x;  // 0..65535
  int j = i & 7, ln = (i >> 3) & 63, kb = (i >> 9) & 3, ct = i >> 11;
  int n = ln & 15, q = ln >> 4;
  int k = kb * 32 + q * 8 + j;
  int col = ct * 16 + n;
  out[i] = __builtin_bit_cast(unsigned short, __float2bfloat16(W[k * CC + col]));
}

// tab[v][col] = embed[v] @ Wi0 + b0   (f32, one-time)
__global__ void xw0tab_kernel(const float* __restrict__ embed, const float* __restrict__ Wi0,
                              const float* __restrict__ b0, float* __restrict__ tab) {
  const int v0 = blockIdx.x * 8;
  const int j = threadIdx.x;  // 256
  __shared__ float A[8][HH];
  for (int s = j; s < 8 * HH; s += 256) {
    int r = s >> 7, k = s & 127;
    int v = v0 + r; if (v >= OUTV) v = OUTV - 1;
    A[r][k] = embed[(size_t)v * HH + k];
  }
  __syncthreads();
  float za[8], zb[8];
  {
    float ba = b0[j], bbv = b0[j + 256];
#pragma unroll
    for (int r = 0; r < 8; ++r) { za[r] = ba; zb[r] = bbv; }
  }
#pragma unroll 4
  for (int k = 0; k < HH; ++k) {
    float wa = Wi0[k * CC + j], wb = Wi0[k * CC + j + 256];
#pragma unroll
    for (int r = 0; r < 8; ++r) { za[r] += A[r][k] * wa; zb[r] += A[r][k] * wb; }
  }
#pragma unroll
  for (int r = 0; r < 8; ++r) {
    tab[(size_t)(v0 + r) * CC + j] = za[r];
    tab[(size_t)(v0 + r) * CC + j + 256] = zb[r];
  }
}

// CSR build over the fixed branch graph: 2 edges per (b,n)
__global__ void edge_count(const int* __restrict__ tb, const int* __restrict__ fb,
                           int* __restrict__ count) {
  int e = blockIdx.x * blockDim.x + threadIdx.x;
  if (e >= 2 * MM) return;
  int b = e >> 9, r = e & 511, n = r >> 1, bit = r & 1;
  int tgt = bit ? fb[b * NN + n] : tb[b * NN + n];
  atomicAdd(&count[b * NN + tgt], 1);
}

__global__ void edge_scan(int* __restrict__ count, int* __restrict__ offs) {
  int b = blockIdx.x, tid = threadIdx.x;
  __shared__ int s[256];
  int v = count[b * NN + tid];
  s[tid] = v;
  __syncthreads();
  for (int off = 1; off < 256; off <<= 1) {
    int t = (tid >= off) ? s[tid - off] : 0;
    __syncthreads();
    s[tid] += t;
    __syncthreads();
  }
  offs[b * NN + tid] = b * 2 * NN + s[tid] - v;
  count[b * NN + tid] = 0;  // reuse as fill cursor
  if (b == 0 && tid == 0) offs[MM] = 2 * MM;
}

__global__ void edge_fill(const int* __restrict__ tb, const int* __restrict__ fb,
                          const int* __restrict__ offs, int* __restrict__ cursor,
                          int* __restrict__ edges) {
  int e = blockIdx.x * blockDim.x + threadIdx.x;
  if (e >= 2 * MM) return;
  int b = e >> 9, r = e & 511, n = r >> 1, bit = r & 1;
  int tgt = bit ? fb[b * NN + n] : tb[b * NN + n];
  int pos = offs[b * NN + tgt] + atomicAdd(&cursor[b * NN + tgt], 1);
  edges[pos] = (n << 1) | bit;
}

// ---------------- fused per-step kernel (agg-prologue + LSTM + branch) ----------------
// Dispatch s: prologue aggregates step s-1's W-bufs (cross-block sync = kernel boundary),
// then runs 4 tokens x 2 layers of LSTM via MFMA, then branch softmax + writeout.
// W-bufs and wt/wf are double-buffered (ping-pong by dispatch parity) to avoid
// intra-dispatch read/write races across blocks of the same batch.

__global__ __launch_bounds__(256, 1) void step_kernel(
    float* __restrict__ Sc0g, float* __restrict__ Sh0g,
    float* __restrict__ Sc1g, float* __restrict__ Sh1g,
    const float* __restrict__ Wr0, const float* __restrict__ Wr1,
    const float* __restrict__ Wr2, const float* __restrict__ Wr3,
    float* __restrict__ Ww0, float* __restrict__ Ww1,
    float* __restrict__ Ww2, float* __restrict__ Ww3,
    const float* __restrict__ wtR, const float* __restrict__ wfR,
    float* __restrict__ wtW, float* __restrict__ wfW,
    const float* __restrict__ ipg,
    const int* __restrict__ offs, const int* __restrict__ edges,
    const float* __restrict__ tab,
    const unsigned short* __restrict__ swzWh0, const unsigned short* __restrict__ swzWi1,
    const unsigned short* __restrict__ swzWh1, const float* __restrict__ b1,
    const float* __restrict__ Wb, const float* __restrict__ bb,
    const int* __restrict__ data, const int* __restrict__ exi,
    const int* __restrict__ steps, int step) {
  const int row0 = blockIdx.x * 16;
  const int b = row0 >> 8;
  const int sb = steps[b];
  const bool aggLive = (step >= 1) && ((step - 1) < sb);
  const bool lstmLive = (step < sb);
  if (!aggLive && !lstmLive) return;

  const int tid = threadIdx.x;
  const int w = tid >> 6;
  const int lane = tid & 63;
  const int n16 = lane & 15, qq = lane >> 4;                    // MFMA B/D lane decomposition
  const int gm = tid & 15, gq = (tid >> 4) & 3, ge = tid >> 6;  // gate-phase mapping

  __shared__ float zbuf[16 * ZP];
  __shared__ float c0L[16 * SP], h0L[16 * SP], c1L[16 * SP], h1L[16 * SP];
  __shared__ unsigned int hA0u[1024], hA1u[1024];
  __shared__ float exitP[4][HH];
  __shared__ float ipL[16];
  __shared__ int toks[64];

  // ----- prologue: aggregate previous step's outputs for this block's 16 nodes
  if (aggLive) {
    const int l = tid & 31;
#pragma unroll
    for (int ni = 0; ni < 2; ++ni) {
      int m = ni * 8 + (tid >> 5);
      int node = row0 + m;
      int beg = offs[node], end = offs[node + 1];
      float a0x = 0.f, a0y = 0.f, a0z = 0.f, a0w = 0.f;
      float a1x = 0.f, a1y = 0.f, a1z = 0.f, a1w = 0.f;
      float a2x = 0.f, a2y = 0.f, a2z = 0.f, a2w = 0.f;
      float a3x = 0.f, a3y = 0.f, a3z = 0.f, a3w = 0.f;
      float wsum = 0.f;
      for (int e = beg; e < end; ++e) {
        int rec = edges[e];
        int src = (b << 8) + (rec >> 1);
        float wv = (rec & 1) ? wfR[src] : wtR[src];
        wsum += wv;
        float4 x0 = ((const float4*)Wr0)[src * 32 + l];
        float4 x1 = ((const float4*)Wr1)[src * 32 + l];
        float4 x2 = ((const float4*)Wr2)[src * 32 + l];
        float4 x3 = ((const float4*)Wr3)[src * 32 + l];
        a0x += wv * x0.x; a0y += wv * x0.y; a0z += wv * x0.z; a0w += wv * x0.w;
        a1x += wv * x1.x; a1y += wv * x1.y; a1z += wv * x1.z; a1w += wv * x1.w;
        a2x += wv * x2.x; a2y += wv * x2.y; a2z += wv * x2.z; a2w += wv * x2.w;
        a3x += wv * x3.x; a3y += wv * x3.y; a3z += wv * x3.z; a3w += wv * x3.w;
      }
      float inv = 1.0f / (wsum + 1e-7f);
      float4 o0 = { a0x * inv, a0y * inv, a0z * inv, a0w * inv };
      float4 o1 = { a1x * inv, a1y * inv, a1z * inv, a1w * inv };
      float4 o2 = { a2x * inv, a2y * inv, a2z * inv, a2w * inv };
      float4 o3 = { a3x * inv, a3y * inv, a3z * inv, a3w * inv };
      ((float4*)c0L)[m * (SP / 4) + l] = o0;
      ((float4*)h0L)[m * (SP / 4) + l] = o1;
      ((float4*)c1L)[m * (SP / 4) + l] = o2;
      ((float4*)h1L)[m * (SP / 4) + l] = o3;
      if (l == 0) ipL[m] = wsum;
      if (!lstmLive) {  // batch dies here: persist final state for final_kernel
        ((float4*)Sc0g)[node * 32 + l] = o0;
        ((float4*)Sh0g)[node * 32 + l] = o1;
        ((float4*)Sc1g)[node * 32 + l] = o2;
        ((float4*)Sh1g)[node * 32 + l] = o3;
      }
    }
  } else {
    // step 0: stage zero-init states + initial ip from global
    for (int s = tid; s < 16 * HH; s += 256) {
      int m = s >> 7, k = s & 127;
      size_t g = (size_t)(row0 + m) * HH + k;
      c0L[m * SP + k] = Sc0g[g];
      h0L[m * SP + k] = Sh0g[g];
      c1L[m * SP + k] = Sc1g[g];
      h1L[m * SP + k] = Sh1g[g];
    }
    if (tid < 16) ipL[tid] = ipg[row0 + tid];
  }
  if (!lstmLive) return;  // block-uniform

  // persistent B fragments (Wh0, Wh1)
  s16x8 B0[8][4], B1[8][4];
  const s16x8* pWh0 = (const s16x8*)swzWh0;
  const s16x8* pWh1 = (const s16x8*)swzWh1;
  const s16x8* pWi1 = (const s16x8*)swzWi1;
#pragma unroll
  for (int ct = 0; ct < 8; ++ct) {
#pragma unroll
    for (int kb = 0; kb < 4; ++kb) {
      int fi = ((w * 8 + ct) * 4 + kb) * 64 + lane;
      B0[ct][kb] = pWh0[fi];
      B1[ct][kb] = pWh1[fi];
    }
  }
  float b1v[8];
#pragma unroll
  for (int ct = 0; ct < 8; ++ct) b1v[ct] = b1[(w * 8 + ct) * 16 + n16];

  const int exnode = exi[b];
  const int exm = exnode - (row0 & (NN - 1));

  if (tid < 64) toks[tid] = data[(row0 + (tid >> 2)) * TT + (tid & 3)];
  __syncthreads();

  // bf16 A-fragments from staged h; pristine exit-row copy before gates overwrite
#pragma unroll
  for (int kb = 0; kb < 4; ++kb) {
    int k = kb * 32 + gq * 8 + ge * 2;
    int du = (kb * 64 + gq * 16 + gm) * 4 + ge;
    hA0u[du] = pack2(h0L[gm * SP + k], h0L[gm * SP + k + 1]);
    hA1u[du] = pack2(h1L[gm * SP + k], h1L[gm * SP + k + 1]);
  }
  if (exm >= 0 && exm < 16 && tid < 128) {
    exitP[0][tid] = c0L[exm * SP + tid];
    exitP[1][tid] = h0L[exm * SP + tid];
    exitP[2][tid] = c1L[exm * SP + tid];
    exitP[3][tid] = h1L[exm * SP + tid];
  }
  __syncthreads();

  const s16x8* hA0v = (const s16x8*)hA0u;
  const s16x8* hA1v = (const s16x8*)hA1u;

  for (int t = 0; t < TT; ++t) {
    // read old-h fragments before this token's gates overwrite them
    s16x8 a0[4], a1b[4];
#pragma unroll
    for (int kb = 0; kb < 4; ++kb) { a0[kb] = hA0v[kb * 64 + lane]; a1b[kb] = hA1v[kb * 64 + lane]; }

    // ----- layer 0 MFMA: z = tab[tok] (+b0 baked in) + h0 @ Wh0; D-init direct from tab
#pragma unroll
    for (int ct = 0; ct < 8; ++ct) {
      int colz = (w * 8 + ct) * 16 + n16;
      f32x4 d;
#pragma unroll
      for (int r = 0; r < 4; ++r)
        d[r] = tab[(size_t)toks[(qq * 4 + r) * 4 + t] * CC + colz];
#pragma unroll
      for (int kb = 0; kb < 4; ++kb)
        d = __builtin_amdgcn_mfma_f32_16x16x32_bf16(a0[kb], B0[ct][kb], d, 0, 0, 0);
#pragma unroll
      for (int r = 0; r < 4; ++r) zbuf[(qq * 4 + r) * ZP + colz] = d[r];
    }
    __syncthreads();

    // ----- gates 0 -> c0, h0 + hA0
#pragma unroll
    for (int kb = 0; kb < 4; ++kb) {
      int k = kb * 32 + gq * 8 + ge * 2;
      float hres[2];
#pragma unroll
      for (int dj = 0; dj < 2; ++dj) {
        int kk = k + dj;
        float zi = zbuf[gm * ZP + kk];
        float zf = zbuf[gm * ZP + 128 + kk];
        float zg = zbuf[gm * ZP + 256 + kk];
        float zo = zbuf[gm * ZP + 384 + kk];
        float c = c0L[gm * SP + kk];
        float cn = sigf(zf) * c + sigf(zi) * tanhr(zg);
        float hn = sigf(zo) * tanhr(cn);
        c0L[gm * SP + kk] = cn;
        h0L[gm * SP + kk] = hn;
        hres[dj] = hn;
      }
      hA0u[(kb * 64 + gq * 16 + gm) * 4 + ge] = pack2(hres[0], hres[1]);
    }
    __syncthreads();

    // ----- layer 1 MFMA: z = b1 + h0new @ Wi1 + h1 @ Wh1
    s16x8 a1a[4];
#pragma unroll
    for (int kb = 0; kb < 4; ++kb) a1a[kb] = hA0v[kb * 64 + lane];
    s16x8 wi[4], win[4];
#pragma unroll
    for (int kb = 0; kb < 4; ++kb) wi[kb] = pWi1[((w * 8) * 4 + kb) * 64 + lane];
#pragma unroll
    for (int ct = 0; ct < 8; ++ct) {
      if (ct < 7) {
#pragma unroll
        for (int kb = 0; kb < 4; ++kb) win[kb] = pWi1[((w * 8 + ct + 1) * 4 + kb) * 64 + lane];
      }
      int colz = (w * 8 + ct) * 16 + n16;
      f32x4 d = { b1v[ct], b1v[ct], b1v[ct], b1v[ct] };
#pragma unroll
      for (int kb = 0; kb < 4; ++kb)
        d = __builtin_amdgcn_mfma_f32_16x16x32_bf16(a1a[kb], wi[kb], d, 0, 0, 0);
#pragma unroll
      for (int kb = 0; kb < 4; ++kb)
        d = __builtin_amdgcn_mfma_f32_16x16x32_bf16(a1b[kb], B1[ct][kb], d, 0, 0, 0);
#pragma unroll
      for (int r = 0; r < 4; ++r) zbuf[(qq * 4 + r) * ZP + colz] = d[r];
#pragma unroll
      for (int kb = 0; kb < 4; ++kb) wi[kb] = win[kb];
    }
    __syncthreads();

    // ----- gates 1 -> c1, h1 + hA1
#pragma unroll
    for (int kb = 0; kb < 4; ++kb) {
      int k = kb * 32 + gq * 8 + ge * 2;
      float hres[2];
#pragma unroll
      for (int dj = 0; dj < 2; ++dj) {
        int kk = k + dj;
        float zi = zbuf[gm * ZP + kk];
        float zf = zbuf[gm * ZP + 128 + kk];
        float zg = zbuf[gm * ZP + 256 + kk];
        float zo = zbuf[gm * ZP + 384 + kk];
        float c = c1L[gm * SP + kk];
        float cn = sigf(zf) * c + sigf(zi) * tanhr(zg);
        float hn = sigf(zo) * tanhr(cn);
        c1L[gm * SP + kk] = cn;
        h1L[gm * SP + kk] = hn;
        hres[dj] = hn;
      }
      hA1u[(kb * 64 + gq * 16 + gm) * 4 + ge] = pack2(hres[0], hres[1]);
    }
    __syncthreads();
  }

  // ----- fused branch softmax (16 threads per row); exit row uses pristine copy
  {
    const int m = tid >> 4, sub = tid & 15;
    const int row = row0 + m;
    const bool isExit = (m == exm);
    float z0 = 0.f, z1 = 0.f;
#pragma unroll
    for (int u = 0; u < 32; ++u) {
      int k = u * 16 + sub;
      int seg = k >> 7, kk = k & 127;
      float fk;
      if (isExit) {
        fk = exitP[seg][kk];
      } else {
        fk = (seg == 0) ? c0L[m * SP + kk] : (seg == 1) ? h0L[m * SP + kk]
           : (seg == 2) ? c1L[m * SP + kk] : h1L[m * SP + kk];
      }
      z0 += fk * Wb[2 * k];
      z1 += fk * Wb[2 * k + 1];
    }
#pragma unroll
    for (int off = 8; off >= 1; off >>= 1) {
      z0 += __shfl_xor(z0, off);
      z1 += __shfl_xor(z1, off);
    }
    if (sub == 0) {
      z0 += bb[0]; z1 += bb[1];
      float mx = fmaxf(z0, z1);
      float e0 = __expf(z0 - mx), e1 = __expf(z1 - mx);
      float inv = 1.0f / (e0 + e1);
      float ipv = ipL[m];
      wtW[row] = e0 * inv * ipv;
      wfW[row] = e1 * inv * ipv;
    }
  }

  // ----- writeout working state to write-set W bufs; exit row from pristine copy
  for (int s = tid; s < 16 * HH; s += 256) {
    int m = s >> 7, k = s & 127;
    bool ex = (m == exm);
    size_t g = (size_t)(row0 + m) * HH + k;
    Ww0[g] = ex ? exitP[0][k] : c0L[m * SP + k];
    Ww1[g] = ex ? exitP[1][k] : h0L[m * SP + k];
    Ww2[g] = ex ? exitP[2][k] : c1L[m * SP + k];
    Ww3[g] = ex ? exitP[3][k] : h1L[m * SP + k];
  }
}

// logits: 64 blocks (16 batches x 4 col-tiles of 250), 256 threads, 1 output/thread
__global__ void final_kernel(const float* __restrict__ Sc0, const float* __restrict__ Sh0,
                             const float* __restrict__ Sc1, const float* __restrict__ Sh1,
                             const int* __restrict__ exi, const float* __restrict__ Wo,
                             const float* __restrict__ bo, float* __restrict__ out) {
  const int b = blockIdx.x >> 2;
  const int vt = blockIdx.x & 3;
  const int tid = threadIdx.x;  // 256
  __shared__ float f[512];
  int row = b * NN + exi[b];
  if (tid < 128) {
    size_t g = (size_t)row * HH + tid;
    f[tid] = Sc0[g];
    f[128 + tid] = Sh0[g];
    f[256 + tid] = Sc1[g];
    f[384 + tid] = Sh1[g];
  }
  __syncthreads();
  if (tid < 250) {
    int v = vt * 250 + tid;
    float acc = bo[v];
#pragma unroll 8
    for (int k = 0; k < 512; ++k) acc += f[k] * Wo[(size_t)k * OUTV + v];
    out[b * OUTV + v] = acc;
  }
}

// distinct failure signature if workspace too small: out := 0 -> err == ref absmax
__global__ void zero_out_kernel(float* __restrict__ out, int n) {
  int i = blockIdx.x * blockDim.x + threadIdx.x;
  if (i < n) out[i] = 0.0f;
}

// ---------------- host orchestration ----------------

extern "C" void kernel_launch(void* const* d_in, const int* in_sizes, int n_in,
                              void* d_out, int out_size, void* d_ws, size_t ws_size,
                              hipStream_t stream) {
  const int* data = (const int*)d_in[0];
  const int* tb   = (const int*)d_in[1];
  const int* fb   = (const int*)d_in[2];
  const int* exi  = (const int*)d_in[3];
  const int* steps = (const int*)d_in[4];
  const float* embed = (const float*)d_in[5];
  const float* Wi = (const float*)d_in[6];   // (L,H,4H)
  const float* Wh = (const float*)d_in[7];   // (L,H,4H)
  const float* bl = (const float*)d_in[8];   // (L,4H)
  const float* Wb = (const float*)d_in[9];   // (2LH,2)
  const float* bb = (const float*)d_in[10];  // (2,)
  const float* Wo = (const float*)d_in[11];  // (2LH,OUT)
  const float* bo = (const float*)d_in[12];  // (OUT,)
  float* out = (float*)d_out;

  const float* Wi0 = Wi;
  const float* Wi1 = Wi + HH * CC;
  const float* Wh0 = Wh;
  const float* Wh1 = Wh + HH * CC;
  const float* b0 = bl;
  const float* b1 = bl + CC;

  float* ws = (float*)d_ws;
  size_t off = 0;
  float* tab = ws + off;  off += (size_t)1024 * CC;        // 2 MB
  float* Sc0 = ws + off;  off += (size_t)MM * HH;          // 4 contiguous S bufs
  float* Sh0 = ws + off;  off += (size_t)MM * HH;
  float* Sc1 = ws + off;  off += (size_t)MM * HH;
  float* Sh1 = ws + off;  off += (size_t)MM * HH;
  float* WA[4], *WB[4];
  for (int i = 0; i < 4; ++i) { WA[i] = ws + off; off += (size_t)MM * HH; }
  for (int i = 0; i < 4; ++i) { WB[i] = ws + off; off += (size_t)MM * HH; }
  unsigned short* swzWh0 = (unsigned short*)(ws + off); off += (size_t)HH * CC / 2;
  unsigned short* swzWi1 = (unsigned short*)(ws + off); off += (size_t)HH * CC / 2;
  unsigned short* swzWh1 = (unsigned short*)(ws + off); off += (size_t)HH * CC / 2;
  float* ip = ws + off;   off += MM;
  float* wtA = ws + off;  off += MM;
  float* wfA = ws + off;  off += MM;
  float* wtB = ws + off;  off += MM;
  float* wfB = ws + off;  off += MM;
  int* count = (int*)(ws + off); off += MM;
  int* offs  = (int*)(ws + off); off += MM + 16;
  int* edges = (int*)(ws + off); off += 2 * MM;
  (void)in_sizes; (void)n_in; (void)out_size;

  if (ws_size < off * sizeof(float)) {
    zero_out_kernel<<<(BB * OUTV + 255) / 256, 256, 0, stream>>>(out, BB * OUTV);
    return;
  }

  init_kernel<<<256, 256, 0, stream>>>(Sc0, ip, count);
  swz_kernel<<<256, 256, 0, stream>>>(Wh0, swzWh0);
  swz_kernel<<<256, 256, 0, stream>>>(Wi1, swzWi1);
  swz_kernel<<<256, 256, 0, stream>>>(Wh1, swzWh1);
  xw0tab_kernel<<<128, 256, 0, stream>>>(embed, Wi0, b0, tab);
  edge_count<<<(2 * MM + 255) / 256, 256, 0, stream>>>(tb, fb, count);
  edge_scan<<<BB, 256, 0, stream>>>(count, offs);
  edge_fill<<<(2 * MM + 255) / 256, 256, 0, stream>>>(tb, fb, offs, count, edges);

  // dispatch s: prologue aggregates step s-1 (reads parity (s+1)&1), LSTM writes parity s&1.
  // s = MAXS is agg-only (lstmLive always false there since steps <= MAXS).
  for (int s = 0; s <= MAXS; ++s) {
    float** Wwr = (s & 1) ? WB : WA;
    float** Wrd = (s & 1) ? WA : WB;
    float* wtWp = (s & 1) ? wtB : wtA;
    float* wfWp = (s & 1) ? wfB : wfA;
    float* wtRp = (s & 1) ? wtA : wtB;
    float* wfRp = (s & 1) ? wfA : wfB;
    step_kernel<<<MM / 16, 256, 0, stream>>>(
        Sc0, Sh0, Sc1, Sh1,
        Wrd[0], Wrd[1], Wrd[2], Wrd[3],
        Wwr[0], Wwr[1], Wwr[2], Wwr[3],
        wtRp, wfRp, wtWp, wfWp, ip,
        offs, edges, tab, swzWh0, swzWi1, swzWh1, b1, Wb, bb,
        data, exi, steps, s);
  }
  final_kernel<<<BB * 4, 256, 0, stream>>>(Sc0, Sh0, Sc1, Sh1, exi, Wo, bo, out);
}

// Round 6
// 596.386 us; speedup vs baseline: 6.9691x; 1.1471x over previous
//
#include <hip/hip_runtime.h>
#include <hip/hip_bf16.h>
#include <stdint.h>
#include <stddef.h>

static constexpr int BB = 16, NN = 256, TT = 4, HH = 128;
static constexpr int MM = BB * NN;     // 4096 rows
static constexpr int CC = 512;         // 4*H gate width
static constexpr int OUTV = 1000;
static constexpr int MAXS = 15;
static constexpr int SP = 132;         // f32 state row pitch

typedef float f32x4 __attribute__((ext_vector_type(4)));
typedef short s16x8 __attribute__((ext_vector_type(8)));

__device__ __forceinline__ float sigf(float x) { return 1.0f / (1.0f + __expf(-x)); }
__device__ __forceinline__ float tanhr(float x) { return 2.0f / (1.0f + __expf(-2.0f * x)) - 1.0f; }
__device__ __forceinline__ unsigned short f2bu(float a) {
  return __builtin_bit_cast(unsigned short, __float2bfloat16(a));
}

// ---------------- setup kernels ----------------

__global__ void init_kernel(float* __restrict__ S, float* __restrict__ ip, int* __restrict__ count) {
  int tid = blockIdx.x * blockDim.x + threadIdx.x;
  int stride = gridDim.x * blockDim.x;
  int total = 4 * MM * HH;
  for (int i = tid; i < total; i += stride) S[i] = 0.0f;
  for (int i = tid; i < MM; i += stride) {
    ip[i] = ((i & (NN - 1)) == 0) ? 1.0f : 0.0f;
    count[i] = 0;
  }
}

// swizzle one 128x512 f32 weight matrix into bf16 B-fragment order:
// out[((ct*4+kb)*64 + q*16+n)*8 + j] = W[kb*32+q*8+j][ct*16+n]
__global__ void swz_kernel(const float* __restrict__ W, unsigned short* __restrict__ out) {
  int i = blockIdx.x * 256 + threadIdx.x;  // 0..65535
  int j = i & 7, ln = (i >> 3) & 63, kb = (i >> 9) & 3, ct = i >> 11;
  int n = ln & 15, q = ln >> 4;
  int k = kb * 32 + q * 8 + j;
  int col = ct * 16 + n;
  out[i] = f2bu(W[k * CC + col]);
}

// tab[v][col] = embed[v] @ Wi0 + b0   (f32, one-time)
__global__ void xw0tab_kernel(const float* __restrict__ embed, const float* __restrict__ Wi0,
                              const float* __restrict__ b0, float* __restrict__ tab) {
  const int v0 = blockIdx.x * 8;
  const int j = threadIdx.x;  // 256
  __shared__ float A[8][HH];
  for (int s = j; s < 8 * HH; s += 256) {
    int r = s >> 7, k = s & 127;
    int v = v0 + r; if (v >= OUTV) v = OUTV - 1;
    A[r][k] = embed[(size_t)v * HH + k];
  }
  __syncthreads();
  float za[8], zb[8];
  {
    float ba = b0[j], bbv = b0[j + 256];
#pragma unroll
    for (int r = 0; r < 8; ++r) { za[r] = ba; zb[r] = bbv; }
  }
#pragma unroll 4
  for (int k = 0; k < HH; ++k) {
    float wa = Wi0[k * CC + j], wb = Wi0[k * CC + j + 256];
#pragma unroll
    for (int r = 0; r < 8; ++r) { za[r] += A[r][k] * wa; zb[r] += A[r][k] * wb; }
  }
#pragma unroll
  for (int r = 0; r < 8; ++r) {
    tab[(size_t)(v0 + r) * CC + j] = za[r];
    tab[(size_t)(v0 + r) * CC + j + 256] = zb[r];
  }
}

// CSR build over the fixed branch graph: 2 edges per (b,n)
__global__ void edge_count(const int* __restrict__ tb, const int* __restrict__ fb,
                           int* __restrict__ count) {
  int e = blockIdx.x * blockDim.x + threadIdx.x;
  if (e >= 2 * MM) return;
  int b = e >> 9, r = e & 511, n = r >> 1, bit = r & 1;
  int tgt = bit ? fb[b * NN + n] : tb[b * NN + n];
  atomicAdd(&count[b * NN + tgt], 1);
}

__global__ void edge_scan(int* __restrict__ count, int* __restrict__ offs) {
  int b = blockIdx.x, tid = threadIdx.x;
  __shared__ int s[256];
  int v = count[b * NN + tid];
  s[tid] = v;
  __syncthreads();
  for (int off = 1; off < 256; off <<= 1) {
    int t = (tid >= off) ? s[tid - off] : 0;
    __syncthreads();
    s[tid] += t;
    __syncthreads();
  }
  offs[b * NN + tid] = b * 2 * NN + s[tid] - v;
  count[b * NN + tid] = 0;  // reuse as fill cursor
  if (b == 0 && tid == 0) offs[MM] = 2 * MM;
}

__global__ void edge_fill(const int* __restrict__ tb, const int* __restrict__ fb,
                          const int* __restrict__ offs, int* __restrict__ cursor,
                          int* __restrict__ edges) {
  int e = blockIdx.x * blockDim.x + threadIdx.x;
  if (e >= 2 * MM) return;
  int b = e >> 9, r = e & 511, n = r >> 1, bit = r & 1;
  int tgt = bit ? fb[b * NN + n] : tb[b * NN + n];
  int pos = offs[b * NN + tgt] + atomicAdd(&cursor[b * NN + tgt], 1);
  edges[pos] = (n << 1) | bit;
}

// ---------------- fused per-step kernel ----------------
// 16 rows/block, 512 threads = 8 waves. Wave w owns column tiles {w, w+8, w+16, w+24}
// = the SAME 16 columns (kcol = w*16 + n16) of all four gates i/f/g/o, so gate math
// happens entirely in MFMA D registers; c-state lives in registers across tokens;
// h round-trips LDS only as bf16 A-fragments (4 ds_write_b16 per lane per layer).

__global__ __launch_bounds__(512, 2) void step_kernel(
    float* __restrict__ Sc0g, float* __restrict__ Sh0g,
    float* __restrict__ Sc1g, float* __restrict__ Sh1g,
    const float* __restrict__ Wr0, const float* __restrict__ Wr1,
    const float* __restrict__ Wr2, const float* __restrict__ Wr3,
    float* __restrict__ Ww0, float* __restrict__ Ww1,
    float* __restrict__ Ww2, float* __restrict__ Ww3,
    const float* __restrict__ wtR, const float* __restrict__ wfR,
    float* __restrict__ wtW, float* __restrict__ wfW,
    const float* __restrict__ ipg,
    const int* __restrict__ offs, const int* __restrict__ edges,
    const float* __restrict__ tab,
    const unsigned short* __restrict__ swzWh0, const unsigned short* __restrict__ swzWi1,
    const unsigned short* __restrict__ swzWh1, const float* __restrict__ b1,
    const float* __restrict__ Wb, const float* __restrict__ bb,
    const int* __restrict__ data, const int* __restrict__ exi,
    const int* __restrict__ steps, int step) {
  const int row0 = blockIdx.x * 16;
  const int b = row0 >> 8;
  const int sb = steps[b];
  const bool aggLive = (step >= 1) && ((step - 1) < sb);
  const bool lstmLive = (step < sb);
  if (!aggLive && !lstmLive) return;

  const int tid = threadIdx.x;
  const int w = tid >> 6;          // wave 0..7
  const int lane = tid & 63;
  const int n16 = lane & 15, qq = lane >> 4;
  const int kcol = w * 16 + n16;   // this lane's gate-column (0..127)

  __shared__ float c0L[16 * SP], h0L[16 * SP], c1L[16 * SP], h1L[16 * SP];
  __shared__ __align__(16) unsigned short hA0[2048], hA1[2048];  // 16 rows x 128 k, frag order
  __shared__ float exitP[4][HH];
  __shared__ float ipL[16];
  __shared__ int toks[64];

  // ----- prologue: aggregate previous step's outputs (16 nodes, 32 lanes each)
  if (aggLive) {
    const int l = tid & 31;
    const int m = tid >> 5;  // 0..15
    const int node = row0 + m;
    int beg = offs[node], end = offs[node + 1];
    float a0x = 0.f, a0y = 0.f, a0z = 0.f, a0w = 0.f;
    float a1x = 0.f, a1y = 0.f, a1z = 0.f, a1w = 0.f;
    float a2x = 0.f, a2y = 0.f, a2z = 0.f, a2w = 0.f;
    float a3x = 0.f, a3y = 0.f, a3z = 0.f, a3w = 0.f;
    float wsum = 0.f;
    for (int e = beg; e < end; ++e) {
      int rec = edges[e];
      int src = (b << 8) + (rec >> 1);
      float wv = (rec & 1) ? wfR[src] : wtR[src];
      wsum += wv;
      float4 x0 = ((const float4*)Wr0)[src * 32 + l];
      float4 x1 = ((const float4*)Wr1)[src * 32 + l];
      float4 x2 = ((const float4*)Wr2)[src * 32 + l];
      float4 x3 = ((const float4*)Wr3)[src * 32 + l];
      a0x += wv * x0.x; a0y += wv * x0.y; a0z += wv * x0.z; a0w += wv * x0.w;
      a1x += wv * x1.x; a1y += wv * x1.y; a1z += wv * x1.z; a1w += wv * x1.w;
      a2x += wv * x2.x; a2y += wv * x2.y; a2z += wv * x2.z; a2w += wv * x2.w;
      a3x += wv * x3.x; a3y += wv * x3.y; a3z += wv * x3.z; a3w += wv * x3.w;
    }
    float inv = 1.0f / (wsum + 1e-7f);
    float4 o0 = { a0x * inv, a0y * inv, a0z * inv, a0w * inv };
    float4 o1 = { a1x * inv, a1y * inv, a1z * inv, a1w * inv };
    float4 o2 = { a2x * inv, a2y * inv, a2z * inv, a2w * inv };
    float4 o3 = { a3x * inv, a3y * inv, a3z * inv, a3w * inv };
    ((float4*)c0L)[m * (SP / 4) + l] = o0;
    ((float4*)h0L)[m * (SP / 4) + l] = o1;
    ((float4*)c1L)[m * (SP / 4) + l] = o2;
    ((float4*)h1L)[m * (SP / 4) + l] = o3;
    if (l == 0) ipL[m] = wsum;
    if (!lstmLive) {  // batch dies here: persist final state for final_kernel
      ((float4*)Sc0g)[node * 32 + l] = o0;
      ((float4*)Sh0g)[node * 32 + l] = o1;
      ((float4*)Sc1g)[node * 32 + l] = o2;
      ((float4*)Sh1g)[node * 32 + l] = o3;
    }
  } else {
    // step 0: stage zero-init states + initial ip from global
    for (int s = tid; s < 16 * HH; s += 512) {
      int m = s >> 7, k = s & 127;
      size_t g = (size_t)(row0 + m) * HH + k;
      c0L[m * SP + k] = Sc0g[g];
      h0L[m * SP + k] = Sh0g[g];
      c1L[m * SP + k] = Sc1g[g];
      h1L[m * SP + k] = Sh1g[g];
    }
    if (tid < 16) ipL[tid] = ipg[row0 + tid];
  }
  if (!lstmLive) return;  // block-uniform

  // persistent B fragments: Wh0, Wh1, tiles ci = w + 8g
  s16x8 B0[4][4], B1[4][4];
  const s16x8* pWh0 = (const s16x8*)swzWh0;
  const s16x8* pWh1 = (const s16x8*)swzWh1;
  const s16x8* pWi1 = (const s16x8*)swzWi1;
  float b1v[4];
#pragma unroll
  for (int g = 0; g < 4; ++g) {
    int ci = w + 8 * g;
#pragma unroll
    for (int kb = 0; kb < 4; ++kb) {
      B0[g][kb] = pWh0[(ci * 4 + kb) * 64 + lane];
      B1[g][kb] = pWh1[(ci * 4 + kb) * 64 + lane];
    }
    b1v[g] = b1[ci * 16 + n16];
  }

  const int exnode = exi[b];
  const int exm = exnode - (row0 & (NN - 1));
  if (tid < 64) toks[tid] = data[(row0 + (tid >> 2)) * TT + (tid & 3)];
  __syncthreads();  // prologue state visible

  // pristine exit-row copy (c/h LDS stays pristine through tokens, but epilogue overwrites)
  if (exm >= 0 && exm < 16 && tid < 128) {
    exitP[0][tid] = c0L[exm * SP + tid];
    exitP[1][tid] = h0L[exm * SP + tid];
    exitP[2][tid] = c1L[exm * SP + tid];
    exitP[3][tid] = h1L[exm * SP + tid];
  }

  // c-state into registers; build bf16 h A-fragments
  const int kb0 = kcol >> 5, q0 = (kcol >> 3) & 3, j0 = kcol & 7;
  const int basePos = (kb0 * 64 + q0 * 16) * 8 + j0;  // + m*8
  float c0r[4], c1r[4], h0r[4], h1r[4];
#pragma unroll
  for (int r = 0; r < 4; ++r) {
    int m = qq * 4 + r;
    c0r[r] = c0L[m * SP + kcol];
    c1r[r] = c1L[m * SP + kcol];
    h0r[r] = h0L[m * SP + kcol];
    h1r[r] = h1L[m * SP + kcol];
    hA0[basePos + m * 8] = f2bu(h0r[r]);
    hA1[basePos + m * 8] = f2bu(h1r[r]);
  }
  __syncthreads();  // fragments ready

  const s16x8* hA0v = (const s16x8*)hA0;
  const s16x8* hA1v = (const s16x8*)hA1;

  for (int t = 0; t < TT; ++t) {
    // read old-h fragments + issue layer-0 D-init loads (tab gather)
    s16x8 a0[4], a1b[4];
#pragma unroll
    for (int kb = 0; kb < 4; ++kb) { a0[kb] = hA0v[kb * 64 + lane]; a1b[kb] = hA1v[kb * 64 + lane]; }
    f32x4 d0[4];
#pragma unroll
    for (int g = 0; g < 4; ++g) {
      int colz = (w + 8 * g) * 16 + n16;
#pragma unroll
      for (int r = 0; r < 4; ++r)
        d0[g][r] = tab[(size_t)toks[(qq * 4 + r) * 4 + t] * CC + colz];
    }
    __syncthreads();  // all frag reads done before overwrites

    // ----- layer 0 MFMA: z = tab(+b0) + h0 @ Wh0 (4 independent 4-chains)
#pragma unroll
    for (int g = 0; g < 4; ++g)
#pragma unroll
      for (int kb = 0; kb < 4; ++kb)
        d0[g] = __builtin_amdgcn_mfma_f32_16x16x32_bf16(a0[kb], B0[g][kb], d0[g], 0, 0, 0);

    // ----- gates 0 entirely in registers
#pragma unroll
    for (int r = 0; r < 4; ++r) {
      float cn = sigf(d0[1][r]) * c0r[r] + sigf(d0[0][r]) * tanhr(d0[2][r]);
      float hn = sigf(d0[3][r]) * tanhr(cn);
      c0r[r] = cn; h0r[r] = hn;
      hA0[basePos + (qq * 4 + r) * 8] = f2bu(hn);
    }
    __syncthreads();  // h0_new fragments visible

    // ----- layer 1 MFMA: z = b1 + h0new @ Wi1 + h1old @ Wh1
    s16x8 a1a[4];
#pragma unroll
    for (int kb = 0; kb < 4; ++kb) a1a[kb] = hA0v[kb * 64 + lane];
    f32x4 d1[4];
#pragma unroll
    for (int g = 0; g < 4; ++g) {
      int ci = w + 8 * g;
      s16x8 wi[4];
#pragma unroll
      for (int kb = 0; kb < 4; ++kb) wi[kb] = pWi1[(ci * 4 + kb) * 64 + lane];
      f32x4 d = { b1v[g], b1v[g], b1v[g], b1v[g] };
#pragma unroll
      for (int kb = 0; kb < 4; ++kb)
        d = __builtin_amdgcn_mfma_f32_16x16x32_bf16(a1a[kb], wi[kb], d, 0, 0, 0);
#pragma unroll
      for (int kb = 0; kb < 4; ++kb)
        d = __builtin_amdgcn_mfma_f32_16x16x32_bf16(a1b[kb], B1[g][kb], d, 0, 0, 0);
      d1[g] = d;
    }

    // ----- gates 1 in registers
#pragma unroll
    for (int r = 0; r < 4; ++r) {
      float cn = sigf(d1[1][r]) * c1r[r] + sigf(d1[0][r]) * tanhr(d1[2][r]);
      float hn = sigf(d1[3][r]) * tanhr(cn);
      c1r[r] = cn; h1r[r] = hn;
      hA1[basePos + (qq * 4 + r) * 8] = f2bu(hn);
    }
    __syncthreads();  // h1_new fragments visible for next token
  }

  // ----- epilogue: write final states from regs to LDS (exitP already saved)
#pragma unroll
  for (int r = 0; r < 4; ++r) {
    int m = qq * 4 + r;
    c0L[m * SP + kcol] = c0r[r];
    h0L[m * SP + kcol] = h0r[r];
    c1L[m * SP + kcol] = c1r[r];
    h1L[m * SP + kcol] = h1r[r];
  }
  __syncthreads();

  // ----- fused branch softmax (32 threads per row); exit row uses pristine copy
  {
    const int m = tid >> 5, sub = tid & 31;
    const int row = row0 + m;
    const bool isExit = (m == exm);
    float z0 = 0.f, z1 = 0.f;
#pragma unroll
    for (int u = 0; u < 16; ++u) {
      int k = u * 32 + sub;
      int seg = k >> 7, kk = k & 127;
      float fk;
      if (isExit) {
        fk = exitP[seg][kk];
      } else {
        fk = (seg == 0) ? c0L[m * SP + kk] : (seg == 1) ? h0L[m * SP + kk]
           : (seg == 2) ? c1L[m * SP + kk] : h1L[m * SP + kk];
      }
      z0 += fk * Wb[2 * k];
      z1 += fk * Wb[2 * k + 1];
    }
#pragma unroll
    for (int off = 16; off >= 1; off >>= 1) {
      z0 += __shfl_xor(z0, off);
      z1 += __shfl_xor(z1, off);
    }
    if (sub == 0) {
      z0 += bb[0]; z1 += bb[1];
      float mx = fmaxf(z0, z1);
      float e0 = __expf(z0 - mx), e1 = __expf(z1 - mx);
      float inv = 1.0f / (e0 + e1);
      float ipv = ipL[m];
      wtW[row] = e0 * inv * ipv;
      wfW[row] = e1 * inv * ipv;
    }
  }

  // ----- writeout working state; exit row from pristine copy
  for (int s = tid; s < 16 * HH; s += 512) {
    int m = s >> 7, k = s & 127;
    bool ex = (m == exm);
    size_t g = (size_t)(row0 + m) * HH + k;
    Ww0[g] = ex ? exitP[0][k] : c0L[m * SP + k];
    Ww1[g] = ex ? exitP[1][k] : h0L[m * SP + k];
    Ww2[g] = ex ? exitP[2][k] : c1L[m * SP + k];
    Ww3[g] = ex ? exitP[3][k] : h1L[m * SP + k];
  }
}

// logits: 64 blocks (16 batches x 4 col-tiles of 250), 256 threads, 1 output/thread
__global__ void final_kernel(const float* __restrict__ Sc0, const float* __restrict__ Sh0,
                             const float* __restrict__ Sc1, const float* __restrict__ Sh1,
                             const int* __restrict__ exi, const float* __restrict__ Wo,
                             const float* __restrict__ bo, float* __restrict__ out) {
  const int b = blockIdx.x >> 2;
  const int vt = blockIdx.x & 3;
  const int tid = threadIdx.x;  // 256
  __shared__ float f[512];
  int row = b * NN + exi[b];
  if (tid < 128) {
    size_t g = (size_t)row * HH + tid;
    f[tid] = Sc0[g];
    f[128 + tid] = Sh0[g];
    f[256 + tid] = Sc1[g];
    f[384 + tid] = Sh1[g];
  }
  __syncthreads();
  if (tid < 250) {
    int v = vt * 250 + tid;
    float acc = bo[v];
#pragma unroll 8
    for (int k = 0; k < 512; ++k) acc += f[k] * Wo[(size_t)k * OUTV + v];
    out[b * OUTV + v] = acc;
  }
}

// distinct failure signature if workspace too small: out := 0 -> err == ref absmax
__global__ void zero_out_kernel(float* __restrict__ out, int n) {
  int i = blockIdx.x * blockDim.x + threadIdx.x;
  if (i < n) out[i] = 0.0f;
}

// ---------------- host orchestration ----------------

extern "C" void kernel_launch(void* const* d_in, const int* in_sizes, int n_in,
                              void* d_out, int out_size, void* d_ws, size_t ws_size,
                              hipStream_t stream) {
  const int* data = (const int*)d_in[0];
  const int* tb   = (const int*)d_in[1];
  const int* fb   = (const int*)d_in[2];
  const int* exi  = (const int*)d_in[3];
  const int* steps = (const int*)d_in[4];
  const float* embed = (const float*)d_in[5];
  const float* Wi = (const float*)d_in[6];   // (L,H,4H)
  const float* Wh = (const float*)d_in[7];   // (L,H,4H)
  const float* bl = (const float*)d_in[8];   // (L,4H)
  const float* Wb = (const float*)d_in[9];   // (2LH,2)
  const float* bb = (const float*)d_in[10];  // (2,)
  const float* Wo = (const float*)d_in[11];  // (2LH,OUT)
  const float* bo = (const float*)d_in[12];  // (OUT,)
  float* out = (float*)d_out;

  const float* Wi0 = Wi;
  const float* Wi1 = Wi + HH * CC;
  const float* Wh0 = Wh;
  const float* Wh1 = Wh + HH * CC;
  const float* b0 = bl;
  const float* b1 = bl + CC;

  float* ws = (float*)d_ws;
  size_t off = 0;
  float* tab = ws + off;  off += (size_t)1024 * CC;        // 2 MB
  float* Sc0 = ws + off;  off += (size_t)MM * HH;          // 4 contiguous S bufs
  float* Sh0 = ws + off;  off += (size_t)MM * HH;
  float* Sc1 = ws + off;  off += (size_t)MM * HH;
  float* Sh1 = ws + off;  off += (size_t)MM * HH;
  float* WA[4], *WB[4];
  for (int i = 0; i < 4; ++i) { WA[i] = ws + off; off += (size_t)MM * HH; }
  for (int i = 0; i < 4; ++i) { WB[i] = ws + off; off += (size_t)MM * HH; }
  unsigned short* swzWh0 = (unsigned short*)(ws + off); off += (size_t)HH * CC / 2;
  unsigned short* swzWi1 = (unsigned short*)(ws + off); off += (size_t)HH * CC / 2;
  unsigned short* swzWh1 = (unsigned short*)(ws + off); off += (size_t)HH * CC / 2;
  float* ip = ws + off;   off += MM;
  float* wtA = ws + off;  off += MM;
  float* wfA = ws + off;  off += MM;
  float* wtB = ws + off;  off += MM;
  float* wfB = ws + off;  off += MM;
  int* count = (int*)(ws + off); off += MM;
  int* offs  = (int*)(ws + off); off += MM + 16;
  int* edges = (int*)(ws + off); off += 2 * MM;
  (void)in_sizes; (void)n_in; (void)out_size;

  if (ws_size < off * sizeof(float)) {
    zero_out_kernel<<<(BB * OUTV + 255) / 256, 256, 0, stream>>>(out, BB * OUTV);
    return;
  }

  init_kernel<<<256, 256, 0, stream>>>(Sc0, ip, count);
  swz_kernel<<<256, 256, 0, stream>>>(Wh0, swzWh0);
  swz_kernel<<<256, 256, 0, stream>>>(Wi1, swzWi1);
  swz_kernel<<<256, 256, 0, stream>>>(Wh1, swzWh1);
  xw0tab_kernel<<<128, 256, 0, stream>>>(embed, Wi0, b0, tab);
  edge_count<<<(2 * MM + 255) / 256, 256, 0, stream>>>(tb, fb, count);
  edge_scan<<<BB, 256, 0, stream>>>(count, offs);
  edge_fill<<<(2 * MM + 255) / 256, 256, 0, stream>>>(tb, fb, offs, count, edges);

  // dispatch s: prologue aggregates step s-1 (reads other parity), LSTM writes parity s&1.
  for (int s = 0; s <= MAXS; ++s) {
    float** Wwr = (s & 1) ? WB : WA;
    float** Wrd = (s & 1) ? WA : WB;
    float* wtWp = (s & 1) ? wtB : wtA;
    float* wfWp = (s & 1) ? wfB : wfA;
    float* wtRp = (s & 1) ? wtA : wtB;
    float* wfRp = (s & 1) ? wfA : wfB;
    step_kernel<<<MM / 16, 512, 0, stream>>>(
        Sc0, Sh0, Sc1, Sh1,
        Wrd[0], Wrd[1], Wrd[2], Wrd[3],
        Wwr[0], Wwr[1], Wwr[2], Wwr[3],
        wtRp, wfRp, wtWp, wfWp, ip,
        offs, edges, tab, swzWh0, swzWi1, swzWh1, b1, Wb, bb,
        data, exi, steps, s);
  }
  final_kernel<<<BB * 4, 256, 0, stream>>>(Sc0, Sh0, Sc1, Sh1, exi, Wo, bo, out);
}